// Round 2
// baseline (1888.625 us; speedup 1.0000x reference)
//
#include <hip/hip_runtime.h>

// ---------------------------------------------------------------------------
// TimeSeriesGCN: B=8192, N=96 nodes, CIN=16, E=768 edges (+96 self loops)
// GCN(16->64) -> GCN(64->32) -> Conv1d(32->64,k7,s2,p3) -> Conv1d(64->128,k5,s2,p2)
// -> Conv1d(128->256,k3,s2,p1) -> flatten 3072 -> fc1(128) -> cls1(128) -> cls2(210)
// Outputs: x [8192,210] then feat [8192,128] concatenated in d_out.
// ---------------------------------------------------------------------------

#define N_NODE 96
#define E_EDGE 768
#define E_TOT  864

// ws layout in floats
#define C3_FLOATS (8192ull*3072ull)
#define OFF_C3   0ull
#define OFF_WT1  (C3_FLOATS)                 // 14336 floats  [c*7+k][64]
#define OFF_WT2  (OFF_WT1 + 14336ull)        // 40960 floats  [c*5+k][128]
#define OFF_WT3  (OFF_WT2 + 40960ull)        // 98304 floats  [c*3+k][256]
#define OFF_PTR  (OFF_WT3 + 98304ull)        // 97 ints (padded to 128)
#define OFF_COLS (OFF_PTR + 128ull)          // 864 ints
#define OFF_NRM  (OFF_COLS + 864ull)         // 864 floats

// ---------------------------------------------------------------------------
// Build CSR for the (shared) GCN aggregation: out[n] = sum_j nrm[j]*in[cols[j]]
// ---------------------------------------------------------------------------
__global__ void prep_edges(const int* __restrict__ eidx, float* __restrict__ ws) {
    __shared__ int rowv[E_TOT];
    __shared__ int colv[E_TOT];
    __shared__ int degi[N_NODE];
    __shared__ int ptr_s[N_NODE + 1];
    __shared__ float dinv[N_NODE];
    const int tid = threadIdx.x;

    for (int e = tid; e < E_TOT; e += 256) {
        int r, c;
        if (e < E_EDGE) { r = eidx[e]; c = eidx[E_EDGE + e]; }
        else            { r = e - E_EDGE; c = r; }
        rowv[e] = r; colv[e] = c;
    }
    for (int n = tid; n < N_NODE; n += 256) degi[n] = 0;
    __syncthreads();
    for (int e = tid; e < E_TOT; e += 256) atomicAdd(&degi[rowv[e]], 1);
    __syncthreads();
    for (int n = tid; n < N_NODE; n += 256)
        dinv[n] = rsqrtf(fmaxf((float)degi[n], 1e-12f));
    if (tid == 0) {
        ptr_s[0] = 0;
        for (int n = 0; n < N_NODE; n++) ptr_s[n + 1] = ptr_s[n] + degi[n];
    }
    __syncthreads();

    int*   gptr  = (int*)(ws + OFF_PTR);
    int*   gcols = (int*)(ws + OFF_COLS);
    float* gnrm  = ws + OFF_NRM;
    if (tid <= N_NODE) gptr[tid] = ptr_s[tid];
    if (tid < N_NODE) {
        int wp = ptr_s[tid];
        for (int e = 0; e < E_TOT; e++) {
            if (rowv[e] == tid) {
                gcols[wp] = colv[e];
                gnrm[wp]  = dinv[tid] * dinv[colv[e]];
                wp++;
            }
        }
    }
}

// ---------------------------------------------------------------------------
// Transpose conv weights: wT[m][o] = w[o][m], m = c*K+k.
// ---------------------------------------------------------------------------
__global__ void prep_wt(const float* __restrict__ w1, const float* __restrict__ w2,
                        const float* __restrict__ w3, float* __restrict__ ws) {
    int idx = blockIdx.x * 256 + threadIdx.x;
    if (idx < 14336) {                      // conv1: [64][32*7]
        int m = idx >> 6, o = idx & 63;
        ws[OFF_WT1 + idx] = w1[o * 224 + m];
    } else if (idx < 14336 + 40960) {       // conv2: [128][64*5]
        int j = idx - 14336;
        int m = j >> 7, o = j & 127;
        ws[OFF_WT2 + j] = w2[o * 320 + m];
    } else if (idx < 153600) {              // conv3: [256][128*3]
        int j = idx - 55296;
        int m = j >> 8, o = j & 255;
        ws[OFF_WT3 + j] = w3[o * 384 + m];
    }
}

// ---------------------------------------------------------------------------
// Fused per-batch-element GCN1 -> GCN2 -> conv1 -> conv2 -> conv3.
// One block per batch element, 256 threads. LDS pool with aliased live ranges:
//   xs  [96][17]   pool[   0..1631]  S1-S2
//   xa  [96][17]   pool[1632..3263]  S2-S3
//   h1  [96][64]   pool[3264..9407]  S3-S4
//   hw2 [96][32]   pool[   0..3071]  S4-S5
//   h2t [32][104]  pool[3264..6591]  S5-S6   (halo 3)
//   c1t [64][56]   pool[6592..10175] S6-S7   (halo 2)
//   c2t [128][28]  pool[   0..3583]  S7-S8   (halo 1)
// NOTE: c2t overlaps h2t in pool[3264..3583] -> c2t halo zeroing MUST happen
// in S7 (after h2t is dead), not in S6 (round-1 bug: stomped live h2t).
// ---------------------------------------------------------------------------
__launch_bounds__(256)
__global__ void fused_gcn_conv(const float* __restrict__ src,
                               const float* __restrict__ g1w, const float* __restrict__ g1b,
                               const float* __restrict__ g2w, const float* __restrict__ g2b,
                               const float* __restrict__ c1b, const float* __restrict__ c2b,
                               const float* __restrict__ c3b,
                               float* __restrict__ ws) {
    __shared__ __align__(16) float pool[10176];
    __shared__ int   ptr_s[97];
    __shared__ int   cols_s[E_TOT];
    __shared__ float nrm_s[E_TOT];

    const int tid = threadIdx.x;
    const int b   = blockIdx.x;

    float* xs  = pool;
    float* xa  = pool + 1632;
    float* h1  = pool + 3264;
    float* hw2 = pool;
    float* h2t = pool + 3264;
    float* c1t = pool + 6592;
    float* c2t = pool;

    const float* wT1 = ws + OFF_WT1;
    const float* wT2 = ws + OFF_WT2;
    const float* wT3 = ws + OFF_WT3;

    // ---- S1: load src[b] transposed -> xs[n][c]; load CSR ----
    for (int i = tid; i < 1536; i += 256) {
        int c = i / 96, n = i % 96;
        xs[n * 17 + c] = src[(size_t)b * 1536 + i];
    }
    {
        const int*   gptr  = (const int*)(ws + OFF_PTR);
        const int*   gcols = (const int*)(ws + OFF_COLS);
        const float* gnrm  = ws + OFF_NRM;
        if (tid < 97) ptr_s[tid] = gptr[tid];
        for (int i = tid; i < E_TOT; i += 256) { cols_s[i] = gcols[i]; nrm_s[i] = gnrm[i]; }
    }
    __syncthreads();

    // ---- S2: xa = Ahat @ x  (aggregate first: 16 ch < 64 ch) ----
    for (int i = tid; i < 1536; i += 256) {
        int n = i >> 4, c = i & 15;
        float s = 0.f;
        int e0 = ptr_s[n], e1 = ptr_s[n + 1];
        for (int j = e0; j < e1; j++) s += nrm_s[j] * xs[cols_s[j] * 17 + c];
        xa[n * 17 + c] = s;
    }
    __syncthreads();

    // ---- S3: h1 = relu(xa @ W1 + b1)  [96][64] ----
    for (int i = tid; i < 6144; i += 256) {
        int n = i >> 6, f = i & 63;
        float s = g1b[f];
#pragma unroll
        for (int c = 0; c < 16; c++) s += xa[n * 17 + c] * g1w[c * 64 + f];
        h1[i] = fmaxf(s, 0.f);
    }
    __syncthreads();

    // ---- S4: hw2 = h1 @ W2  [96][32]  (aggregate after: 32 ch < 64 ch) ----
    for (int i = tid; i < 3072; i += 256) {
        int n = i >> 5, g = i & 31;
        float s = 0.f;
#pragma unroll 8
        for (int c = 0; c < 64; c++) s += h1[n * 64 + c] * g2w[c * 32 + g];
        hw2[i] = s;
    }
    __syncthreads();

    // ---- S5: h2t = relu(Ahat @ hw2 + b2), transposed to [ch][pos+halo3];
    //          zero h2t halo; zero c1t halo (region is dead h1 tail) ----
    {   // h2t halo: cols {0,1,2,99..103} for 32 channels
        int i = tid;
        if (i < 256) {
            int g = i >> 3, hh = i & 7;
            int col = hh < 3 ? hh : 96 + hh;
            h2t[g * 104 + col] = 0.f;
        }
    }
    for (int i = tid; i < 512; i += 256) {   // c1t halo: cols {0,1,50..55}
        int o = i >> 3, hh = i & 7;
        int col = hh < 2 ? hh : 48 + hh;
        c1t[o * 56 + col] = 0.f;
    }
    for (int i = tid; i < 3072; i += 256) {
        int n = i >> 5, g = i & 31;
        float s = g2b[g];
        int e0 = ptr_s[n], e1 = ptr_s[n + 1];
        for (int j = e0; j < e1; j++) s += nrm_s[j] * hw2[cols_s[j] * 32 + g];
        h2t[g * 104 + 3 + n] = fmaxf(s, 0.f);
    }
    __syncthreads();

    // ---- S6: conv1  32ch x 96 -> 64ch x 48 (k7 s2 p3) ----
    {
        const int o  = tid & 63;
        const int lg = tid >> 6;          // 4 groups of 12 output positions
        float acc[12];
#pragma unroll
        for (int l = 0; l < 12; l++) acc[l] = 0.f;
        const int ibase = 24 * lg;        // col = pos+3
#pragma unroll 2
        for (int c = 0; c < 32; c++) {
            float in_f[32];
            const float4* ip = (const float4*)&h2t[c * 104 + ibase];
#pragma unroll
            for (int t = 0; t < 8; t++) {
                float4 v = ip[t];
                in_f[4*t+0] = v.x; in_f[4*t+1] = v.y; in_f[4*t+2] = v.z; in_f[4*t+3] = v.w;
            }
            float wv[7];
#pragma unroll
            for (int k = 0; k < 7; k++) wv[k] = wT1[(c * 7 + k) * 64 + o];
#pragma unroll
            for (int l = 0; l < 12; l++)
#pragma unroll
                for (int k = 0; k < 7; k++)
                    acc[l] += wv[k] * in_f[2 * l + k];
        }
        float bias = c1b[o];
#pragma unroll
        for (int l = 0; l < 12; l++)
            c1t[o * 56 + 2 + 12 * lg + l] = fmaxf(acc[l] + bias, 0.f);
    }
    __syncthreads();

    // ---- S7: zero c2t halo (h2t now dead; c2t overlaps old h2t region),
    //          then conv2  64ch x 48 -> 128ch x 24 (k5 s2 p2) ----
    for (int i = tid; i < 512; i += 256) {   // c2t halo: cols {0,25,26,27}
        int o = i >> 2, hh = i & 3;
        int col = (hh == 0) ? 0 : 24 + hh;
        c2t[o * 28 + col] = 0.f;
    }
    {
        const int o  = tid & 127;
        const int lg = tid >> 7;          // 2 groups of 12
        float acc[12];
#pragma unroll
        for (int l = 0; l < 12; l++) acc[l] = 0.f;
        const int ibase = 24 * lg;        // col = pos+2
#pragma unroll 2
        for (int c = 0; c < 64; c++) {
            float in_f[32];
            const float4* ip = (const float4*)&c1t[c * 56 + ibase];
#pragma unroll
            for (int t = 0; t < 8; t++) {
                float4 v = ip[t];
                in_f[4*t+0] = v.x; in_f[4*t+1] = v.y; in_f[4*t+2] = v.z; in_f[4*t+3] = v.w;
            }
            float wv[5];
#pragma unroll
            for (int k = 0; k < 5; k++) wv[k] = wT2[(c * 5 + k) * 128 + o];
#pragma unroll
            for (int l = 0; l < 12; l++)
#pragma unroll
                for (int k = 0; k < 5; k++)
                    acc[l] += wv[k] * in_f[2 * l + k];
        }
        float bias = c2b[o];
#pragma unroll
        for (int l = 0; l < 12; l++)
            c2t[o * 28 + 1 + 12 * lg + l] = fmaxf(acc[l] + bias, 0.f);
    }
    __syncthreads();

    // ---- S8: conv3  128ch x 24 -> 256ch x 12 (k3 s2 p1); write to ws ----
    {
        const int o = tid;                // 0..255
        float acc[12];
#pragma unroll
        for (int l = 0; l < 12; l++) acc[l] = 0.f;
#pragma unroll 2
        for (int c = 0; c < 128; c++) {
            float in_f[28];
            const float4* ip = (const float4*)&c2t[c * 28];
#pragma unroll
            for (int t = 0; t < 7; t++) {
                float4 v = ip[t];
                in_f[4*t+0] = v.x; in_f[4*t+1] = v.y; in_f[4*t+2] = v.z; in_f[4*t+3] = v.w;
            }
            float wv[3];
#pragma unroll
            for (int k = 0; k < 3; k++) wv[k] = wT3[(c * 3 + k) * 256 + o];
#pragma unroll
            for (int l = 0; l < 12; l++)
#pragma unroll
                for (int k = 0; k < 3; k++)
                    acc[l] += wv[k] * in_f[2 * l + k];
        }
        float bias = c3b[o];
        float* dst = ws + OFF_C3 + (size_t)b * 3072 + o * 12;
#pragma unroll
        for (int t = 0; t < 3; t++) {
            float4 v;
            v.x = fmaxf(acc[4*t+0] + bias, 0.f);
            v.y = fmaxf(acc[4*t+1] + bias, 0.f);
            v.z = fmaxf(acc[4*t+2] + bias, 0.f);
            v.w = fmaxf(acc[4*t+3] + bias, 0.f);
            *(float4*)&dst[4 * t] = v;
        }
    }
}

// ---------------------------------------------------------------------------
// FC head: feat = c3 @ fc1_w + b (write pre-relu), r = relu(feat),
// r1 = relu(r @ cls1_w + b), x = r1 @ cls2_w + b (write).
// ---------------------------------------------------------------------------
__launch_bounds__(256)
__global__ void fc_head(const float* __restrict__ ws,
                        const float* __restrict__ fc1w, const float* __restrict__ fc1b,
                        const float* __restrict__ cl1w, const float* __restrict__ cl1b,
                        const float* __restrict__ cl2w, const float* __restrict__ cl2b,
                        float* __restrict__ dout) {
    __shared__ __align__(16) float c3s[32 * 33];
    __shared__ __align__(16) float fr[32 * 128];

    const int tid = threadIdx.x;
    const int b0  = blockIdx.x * 32;
    const int tr  = tid >> 5;     // 0..7 -> rows tr*4 .. tr*4+3
    const int tc  = tid & 31;     // cols tc*4 .. tc*4+3
    const float* c3g = ws + OFF_C3;

    float acc[4][4];
#pragma unroll
    for (int q = 0; q < 4; q++)
#pragma unroll
        for (int d = 0; d < 4; d++) acc[q][d] = 0.f;

    // fc1: [32 x 3072] @ [3072 x 128]
    for (int m0 = 0; m0 < 3072; m0 += 32) {
        for (int i = tid; i < 1024; i += 256) {
            int r = i >> 5, j = i & 31;
            c3s[r * 33 + j] = c3g[(size_t)(b0 + r) * 3072 + m0 + j];
        }
        __syncthreads();
#pragma unroll 4
        for (int j = 0; j < 32; j++) {
            float4 w = *(const float4*)&fc1w[(m0 + j) * 128 + tc * 4];
#pragma unroll
            for (int q = 0; q < 4; q++) {
                float a = c3s[(tr * 4 + q) * 33 + j];
                acc[q][0] += a * w.x; acc[q][1] += a * w.y;
                acc[q][2] += a * w.z; acc[q][3] += a * w.w;
            }
        }
        __syncthreads();
    }

    // feat out (pre-relu) + relu into LDS
    {
        float4 bv = *(const float4*)&fc1b[tc * 4];
        float* feat_out = dout + 8192ull * 210ull;
#pragma unroll
        for (int q = 0; q < 4; q++) {
            int row = b0 + tr * 4 + q;
            float4 v;
            v.x = acc[q][0] + bv.x; v.y = acc[q][1] + bv.y;
            v.z = acc[q][2] + bv.z; v.w = acc[q][3] + bv.w;
            *(float4*)&feat_out[(size_t)row * 128 + tc * 4] = v;
            float4 rv;
            rv.x = fmaxf(v.x, 0.f); rv.y = fmaxf(v.y, 0.f);
            rv.z = fmaxf(v.z, 0.f); rv.w = fmaxf(v.w, 0.f);
            *(float4*)&fr[(tr * 4 + q) * 128 + tc * 4] = rv;
        }
    }
    __syncthreads();

    // cls1: [32 x 128] @ [128 x 128], relu, back into fr
    float a2[4][4];
#pragma unroll
    for (int q = 0; q < 4; q++)
#pragma unroll
        for (int d = 0; d < 4; d++) a2[q][d] = 0.f;
#pragma unroll 4
    for (int k = 0; k < 128; k++) {
        float4 w = *(const float4*)&cl1w[k * 128 + tc * 4];
#pragma unroll
        for (int q = 0; q < 4; q++) {
            float a = fr[(tr * 4 + q) * 128 + k];
            a2[q][0] += a * w.x; a2[q][1] += a * w.y;
            a2[q][2] += a * w.z; a2[q][3] += a * w.w;
        }
    }
    __syncthreads();
    {
        float4 bv = *(const float4*)&cl1b[tc * 4];
#pragma unroll
        for (int q = 0; q < 4; q++) {
            float4 rv;
            rv.x = fmaxf(a2[q][0] + bv.x, 0.f); rv.y = fmaxf(a2[q][1] + bv.y, 0.f);
            rv.z = fmaxf(a2[q][2] + bv.z, 0.f); rv.w = fmaxf(a2[q][3] + bv.w, 0.f);
            *(float4*)&fr[(tr * 4 + q) * 128 + tc * 4] = rv;
        }
    }
    __syncthreads();

    // cls2: [32 x 128] @ [128 x 210] in two column passes
    for (int pass = 0; pass < 2; pass++) {
        int c0 = pass * 128 + tc * 4;
        if (c0 >= 210) continue;
        float a3[4][4];
#pragma unroll
        for (int q = 0; q < 4; q++)
#pragma unroll
            for (int d = 0; d < 4; d++) a3[q][d] = 0.f;
        for (int k = 0; k < 128; k++) {
            float wv[4];
#pragma unroll
            for (int d = 0; d < 4; d++)
                wv[d] = (c0 + d < 210) ? cl2w[k * 210 + c0 + d] : 0.f;
#pragma unroll
            for (int q = 0; q < 4; q++) {
                float a = fr[(tr * 4 + q) * 128 + k];
#pragma unroll
                for (int d = 0; d < 4; d++) a3[q][d] += a * wv[d];
            }
        }
#pragma unroll
        for (int q = 0; q < 4; q++) {
            int row = b0 + tr * 4 + q;
#pragma unroll
            for (int d = 0; d < 4; d++) {
                if (c0 + d < 210)
                    dout[(size_t)row * 210 + c0 + d] = a3[q][d] + cl2b[c0 + d];
            }
        }
    }
}

// ---------------------------------------------------------------------------
extern "C" void kernel_launch(void* const* d_in, const int* in_sizes, int n_in,
                              void* d_out, int out_size, void* d_ws, size_t ws_size,
                              hipStream_t stream) {
    const float* src  = (const float*)d_in[0];
    const int*   eidx = (const int*)  d_in[1];
    const float* g1w  = (const float*)d_in[2];
    const float* g1b  = (const float*)d_in[3];
    const float* g2w  = (const float*)d_in[4];
    const float* g2b  = (const float*)d_in[5];
    const float* cv1w = (const float*)d_in[6];
    const float* cv1b = (const float*)d_in[7];
    const float* cv2w = (const float*)d_in[8];
    const float* cv2b = (const float*)d_in[9];
    const float* cv3w = (const float*)d_in[10];
    const float* cv3b = (const float*)d_in[11];
    const float* fc1w = (const float*)d_in[12];
    const float* fc1b = (const float*)d_in[13];
    const float* cl1w = (const float*)d_in[14];
    const float* cl1b = (const float*)d_in[15];
    const float* cl2w = (const float*)d_in[16];
    const float* cl2b = (const float*)d_in[17];
    float* ws  = (float*)d_ws;
    float* out = (float*)d_out;

    prep_edges<<<1, 256, 0, stream>>>(eidx, ws);
    prep_wt<<<600, 256, 0, stream>>>(cv1w, cv2w, cv3w, ws);
    fused_gcn_conv<<<8192, 256, 0, stream>>>(src, g1w, g1b, g2w, g2b,
                                             cv1b, cv2b, cv3b, ws);
    fc_head<<<256, 256, 0, stream>>>(ws, fc1w, fc1b, cl1w, cl1b, cl2w, cl2b, out);
}

// Round 3
// 609.765 us; speedup vs baseline: 3.0973x; 3.0973x over previous
//
#include <hip/hip_runtime.h>

// ---------------------------------------------------------------------------
// TimeSeriesGCN — bf16 MFMA pipeline, batch-as-M GEMMs on position-major slabs.
// B=8192, N=96, CIN=16, E=768(+96 loops).
// trans_agg1:  src -> xa[96][8192][32]   (AhatX, ch16..31 zero)
// gcn12:       xa -> hw2[96][8192][32]   (relu(xa W1+b1) W2, fused)
// agg2:        hw2 -> h2[96][8192][32]   (relu(Ahat hw2 + b2))
// conv1/2/3:   slab GEMMs -> c1[48][8192][64], c2[24][8192][128], c3[12][8192][256]
// fc1:         c3 -> feat(fp32, d_out) + fr(bf16 relu)
// cls1:        fr -> r2 (relu); cls2: r2 -> logits (fp32, d_out)
// ---------------------------------------------------------------------------

typedef __attribute__((ext_vector_type(8))) short short8v;
typedef __attribute__((ext_vector_type(4))) float floatx4;

#define N_NODE 96
#define E_TOT  864
#define BATCH  8192ull

// ws layout, ushort elements
#define R0_OFF   0ull           // 25165824 ushorts (50.33 MB)
#define R1_OFF   25165824ull
#define FR_OFF   50331648ull    // 8192*128
#define R2_OFF   51380224ull
#define WT_OFF   52428800ull
#define W1N_OFF  (WT_OFF + 0)       // [64][32]
#define W2N_OFF  (WT_OFF + 2048)    // [32][64]
#define WC1_OFF  (WT_OFF + 4096)    // [64][224]
#define WC2_OFF  (WT_OFF + 18432)   // [128][320]
#define WC3_OFF  (WT_OFF + 59392)   // [256][384]
#define WF1_OFF  (WT_OFF + 157696)  // [128][3072]
#define WL1_OFF  (WT_OFF + 550912)  // [128][128]
#define WL2_OFF  (WT_OFF + 567296)  // [256][128]
// CSR, int elements from (int*)d_ws
#define PTR_I    26514432ull
#define COLS_I   26514560ull
#define NRM_I    26515456ull

__device__ __forceinline__ unsigned short f2b(float f) {
    unsigned int u = __builtin_bit_cast(unsigned int, f);
    u += 0x7fffu + ((u >> 16) & 1u);
    return (unsigned short)(u >> 16);
}
__device__ __forceinline__ float b2f(unsigned short h) {
    unsigned int u = ((unsigned int)h) << 16;
    return __builtin_bit_cast(float, u);
}

// ---------------------------------------------------------------------------
__global__ void prep_edges(const int* __restrict__ eidx, int* __restrict__ gptr,
                           int* __restrict__ gcols, float* __restrict__ gnrm) {
    __shared__ int rowv[E_TOT];
    __shared__ int colv[E_TOT];
    __shared__ int degi[N_NODE];
    __shared__ int ptr_s[N_NODE + 1];
    __shared__ float dinv[N_NODE];
    const int tid = threadIdx.x;
    for (int e = tid; e < E_TOT; e += 256) {
        int r, c;
        if (e < 768) { r = eidx[e]; c = eidx[768 + e]; }
        else         { r = e - 768; c = r; }
        rowv[e] = r; colv[e] = c;
    }
    for (int n = tid; n < N_NODE; n += 256) degi[n] = 0;
    __syncthreads();
    for (int e = tid; e < E_TOT; e += 256) atomicAdd(&degi[rowv[e]], 1);
    __syncthreads();
    for (int n = tid; n < N_NODE; n += 256)
        dinv[n] = rsqrtf(fmaxf((float)degi[n], 1e-12f));
    if (tid == 0) {
        ptr_s[0] = 0;
        for (int n = 0; n < N_NODE; n++) ptr_s[n + 1] = ptr_s[n] + degi[n];
    }
    __syncthreads();
    if (tid <= N_NODE) gptr[tid] = ptr_s[tid];
    if (tid < N_NODE) {
        int wp = ptr_s[tid];
        for (int e = 0; e < E_TOT; e++) {
            if (rowv[e] == tid) {
                gcols[wp] = colv[e];
                gnrm[wp]  = dinv[tid] * dinv[colv[e]];
                wp++;
            }
        }
    }
}

// ---------------------------------------------------------------------------
// Build all n-major bf16 weight matrices.
// ---------------------------------------------------------------------------
__global__ void prep_weights(const float* __restrict__ g1w, const float* __restrict__ g2w,
                             const float* __restrict__ w1, const float* __restrict__ w2,
                             const float* __restrict__ w3, const float* __restrict__ f1,
                             const float* __restrict__ l1, const float* __restrict__ l2,
                             unsigned short* __restrict__ wt) {
    long idx = (long)blockIdx.x * 256 + threadIdx.x;
    if (idx >= 600064) return;
    float v;
    if (idx < 2048) {                       // w1n[o][c], c>=16 zero-pad
        int o = idx >> 5, c = idx & 31;
        v = (c < 16) ? g1w[c * 64 + o] : 0.f;
    } else if (idx < 4096) {                // w2n[g][c]
        long j = idx - 2048; int g = j >> 6, c = j & 63;
        v = g2w[c * 32 + g];
    } else if (idx < 18432) {               // wc1[o][t*32+c]
        long j = idx - 4096; int o = j / 224, m = j % 224, t = m >> 5, c = m & 31;
        v = w1[o * 224 + c * 7 + t];
    } else if (idx < 59392) {               // wc2[o][t*64+c]
        long j = idx - 18432; int o = j / 320, m = j % 320, t = m >> 6, c = m & 63;
        v = w2[o * 320 + c * 5 + t];
    } else if (idx < 157696) {              // wc3[o][t*128+c]
        long j = idx - 59392; int o = j / 384, m = j % 384, t = m >> 7, c = m & 127;
        v = w3[o * 384 + c * 3 + t];
    } else if (idx < 550912) {              // wf1[f][t*256+o]
        long j = idx - 157696; int f = j / 3072, m = j % 3072, t = m >> 8, o = m & 255;
        v = f1[(o * 12 + t) * 128 + f];
    } else if (idx < 567296) {              // wl1[f2][f1]
        long j = idx - 550912; int f2 = j >> 7, ff = j & 127;
        v = l1[ff * 128 + f2];
    } else {                                // wl2[n][f], n>=210 zero
        long j = idx - 567296; int n = j >> 7, f = j & 127;
        v = (n < 210) ? l2[f * 210 + n] : 0.f;
    }
    wt[idx] = f2b(v);
}

// ---------------------------------------------------------------------------
// Transpose + GCN1 aggregation fused: xa[n][b][c] = sum_j nrm_j src[b][c][col_j]
// 8 batch rows per block; whole graph in LDS. Output 32ch (16..31 zero).
// ---------------------------------------------------------------------------
__launch_bounds__(256)
__global__ void trans_agg1(const float* __restrict__ src,
                           const int* __restrict__ gptr, const int* __restrict__ gcols,
                           const float* __restrict__ gnrm, unsigned short* __restrict__ xa) {
    __shared__ __align__(16) float xs[8 * 1544];   // [bl][c*96+n], padded stride
    __shared__ int ptr_s[97];
    __shared__ int cols_s[E_TOT];
    __shared__ float nrm_s[E_TOT];
    const int tid = threadIdx.x;
    const int b0 = blockIdx.x * 8;
    if (tid < 97) ptr_s[tid] = gptr[tid];
    for (int i = tid; i < E_TOT; i += 256) { cols_s[i] = gcols[i]; nrm_s[i] = gnrm[i]; }
    for (int u = tid; u < 3072; u += 256) {
        int bl = u / 384, j = u % 384;
        float4 v = *(const float4*)&src[((size_t)(b0 + bl)) * 1536 + j * 4];
        *(float4*)&xs[bl * 1544 + j * 4] = v;
    }
    __syncthreads();
    for (int u = tid; u < 768; u += 256) {
        int n = u >> 3, bl = u & 7;
        float a[16];
#pragma unroll
        for (int c = 0; c < 16; c++) a[c] = 0.f;
        int e0 = ptr_s[n], e1 = ptr_s[n + 1];
        for (int j = e0; j < e1; j++) {
            int s = cols_s[j]; float wv = nrm_s[j];
            const float* base = &xs[bl * 1544 + s];
#pragma unroll
            for (int c = 0; c < 16; c++) a[c] += wv * base[c * 96];
        }
        unsigned int d[8];
#pragma unroll
        for (int c2 = 0; c2 < 8; c2++)
            d[c2] = (unsigned int)f2b(a[2 * c2]) | ((unsigned int)f2b(a[2 * c2 + 1]) << 16);
        unsigned int* o = (unsigned int*)(xa + ((size_t)n * BATCH + b0 + bl) * 32);
        *(uint4*)&o[0] = make_uint4(d[0], d[1], d[2], d[3]);
        *(uint4*)&o[4] = make_uint4(d[4], d[5], d[6], d[7]);
        *(uint4*)&o[8]  = make_uint4(0, 0, 0, 0);
        *(uint4*)&o[12] = make_uint4(0, 0, 0, 0);
    }
}

// ---------------------------------------------------------------------------
// Fused GCN1+GCN2 GEMM: hw2 = relu(xa W1 + b1) W2, per node slab.
// grid (64, 1, 96), 256 threads, BM=128.
// ---------------------------------------------------------------------------
__launch_bounds__(256)
__global__ void gcn12(const unsigned short* __restrict__ xa,
                      const unsigned short* __restrict__ w1n,
                      const unsigned short* __restrict__ w2n,
                      const float* __restrict__ b1, unsigned short* __restrict__ hw2) {
    __shared__ __align__(16) unsigned short As[128 * 40];
    __shared__ __align__(16) unsigned short B1s[64 * 40];
    __shared__ __align__(16) unsigned short H1s[128 * 72];
    __shared__ __align__(16) unsigned short B2s[32 * 72];
    const int tid = threadIdx.x;
    const size_t b0 = blockIdx.x * 128;
    const int l = blockIdx.z;
    const int w = tid >> 6, lane = tid & 63, quad = lane >> 4, m16 = lane & 15;

    for (int u = tid; u < 512; u += 256) {     // A: 128 rows x 4 vec8
        int r = u >> 2, cc = u & 3;
        *(short8v*)&As[r * 40 + cc * 8] =
            *(const short8v*)&xa[((size_t)l * BATCH + b0 + r) * 32 + cc * 8];
    }
    for (int u = tid; u < 256; u += 256) {     // B1: 64 x 4
        int r = u >> 2, cc = u & 3;
        *(short8v*)&B1s[r * 40 + cc * 8] = *(const short8v*)&w1n[r * 32 + cc * 8];
    }
    for (int u = tid; u < 256; u += 256) {     // B2: 32 x 8
        int r = u >> 3, cc = u & 7;
        *(short8v*)&B2s[r * 72 + cc * 8] = *(const short8v*)&w2n[r * 64 + cc * 8];
    }
    __syncthreads();

    // stage 1: [128][32] x [32][64]
    {
        const int wm = w >> 1, wq = w & 1;
        const int mbase = wm * 64, nbase = wq * 32;
        floatx4 acc[4][2] = {};
#pragma unroll
        for (int fn = 0; fn < 2; fn++) {
            short8v bfr = *(short8v*)&B1s[(nbase + fn * 16 + m16) * 40 + quad * 8];
#pragma unroll
            for (int fm = 0; fm < 4; fm++) {
                short8v afr = *(short8v*)&As[(mbase + fm * 16 + m16) * 40 + quad * 8];
                acc[fm][fn] = __builtin_amdgcn_mfma_f32_16x16x32_bf16(afr, bfr, acc[fm][fn], 0, 0, 0);
            }
        }
        float bv0 = b1[nbase + m16], bv1 = b1[nbase + 16 + m16];
#pragma unroll
        for (int fm = 0; fm < 4; fm++)
#pragma unroll
            for (int r = 0; r < 4; r++) {
                int row = mbase + fm * 16 + quad * 4 + r;
                H1s[row * 72 + nbase + m16]      = f2b(fmaxf(acc[fm][0][r] + bv0, 0.f));
                H1s[row * 72 + nbase + 16 + m16] = f2b(fmaxf(acc[fm][1][r] + bv1, 0.f));
            }
    }
    __syncthreads();

    // stage 2: [128][64] x [64][32]
    {
        const int mb2 = w * 32;
        floatx4 acc[2][2] = {};
#pragma unroll
        for (int kk = 0; kk < 64; kk += 32)
#pragma unroll
            for (int fn = 0; fn < 2; fn++) {
                short8v bfr = *(short8v*)&B2s[(fn * 16 + m16) * 72 + kk + quad * 8];
#pragma unroll
                for (int fm = 0; fm < 2; fm++) {
                    short8v afr = *(short8v*)&H1s[(mb2 + fm * 16 + m16) * 72 + kk + quad * 8];
                    acc[fm][fn] = __builtin_amdgcn_mfma_f32_16x16x32_bf16(afr, bfr, acc[fm][fn], 0, 0, 0);
                }
            }
        unsigned short* Cs = As;   // reuse (no bias/relu here)
#pragma unroll
        for (int fm = 0; fm < 2; fm++)
#pragma unroll
            for (int r = 0; r < 4; r++) {
                int row = mb2 + fm * 16 + quad * 4 + r;
                Cs[row * 40 + m16]      = f2b(acc[fm][0][r]);
                Cs[row * 40 + 16 + m16] = f2b(acc[fm][1][r]);
            }
    }
    __syncthreads();
    for (int u = tid; u < 512; u += 256) {
        int r = u >> 2, cc = u & 3;
        *(short8v*)&hw2[((size_t)l * BATCH + b0 + r) * 32 + cc * 8] =
            *(short8v*)&As[r * 40 + cc * 8];
    }
}

// ---------------------------------------------------------------------------
// agg2: h2[n][b][g] = relu(sum_j nrm_j hw2[col_j][b][g] + b2[g])
// grid (96, 8): x = node (L2 locality over shared sources), y = b-chunk 1024.
// ---------------------------------------------------------------------------
__launch_bounds__(256)
__global__ void agg2(const unsigned short* __restrict__ hw2,
                     const int* __restrict__ gptr, const int* __restrict__ gcols,
                     const float* __restrict__ gnrm, const float* __restrict__ b2,
                     unsigned short* __restrict__ h2) {
    __shared__ int cols_s[E_TOT];
    __shared__ float nrm_s[E_TOT];
    __shared__ int e0s, e1s;
    const int tid = threadIdx.x;
    const int n = blockIdx.x;
    const size_t b0 = (size_t)blockIdx.y * 1024;
    if (tid == 0) { e0s = gptr[n]; e1s = gptr[n + 1]; }
    for (int i = tid; i < E_TOT; i += 256) { cols_s[i] = gcols[i]; nrm_s[i] = gnrm[i]; }
    __syncthreads();
    const int e0 = e0s, e1 = e1s;
    float bias[8];
    for (int u = tid; u < 4096; u += 256) {
        int bl = u >> 2, cc = u & 3;
#pragma unroll
        for (int i = 0; i < 8; i++) bias[i] = b2[cc * 8 + i];
        float a[8];
#pragma unroll
        for (int i = 0; i < 8; i++) a[i] = bias[i];
        for (int j = e0; j < e1; j++) {
            size_t s = (size_t)cols_s[j];
            float wv = nrm_s[j];
            uint4 g = *(const uint4*)&hw2[(s * BATCH + b0 + bl) * 32 + cc * 8];
            unsigned int gg[4] = {g.x, g.y, g.z, g.w};
#pragma unroll
            for (int p = 0; p < 4; p++) {
                a[2 * p]     += wv * b2f((unsigned short)(gg[p] & 0xffff));
                a[2 * p + 1] += wv * b2f((unsigned short)(gg[p] >> 16));
            }
        }
        unsigned int d[4];
#pragma unroll
        for (int p = 0; p < 4; p++)
            d[p] = (unsigned int)f2b(fmaxf(a[2 * p], 0.f)) |
                   ((unsigned int)f2b(fmaxf(a[2 * p + 1], 0.f)) << 16);
        *(uint4*)&h2[((size_t)n * BATCH + b0 + bl) * 32 + cc * 8] =
            make_uint4(d[0], d[1], d[2], d[3]);
    }
}

// ---------------------------------------------------------------------------
// Unified slab GEMM. A slabs [LIN][B][CIN] bf16; W n-major [NOUT][NTAP*CIN].
// BM=128, BN=64, 4 waves as 2x2. MODE: 0 = bf16 out +bias+relu;
// 2 = fc1 (fp32 feat pre-relu -> outf[128-stride], bf16 relu -> outb);
// 4 = cls2 (fp32 -> outf[210-stride], bias, mask col<210).
// ---------------------------------------------------------------------------
template<int NTAP, int CIN, int NOUT, int STRIDE, int PAD, int LIN, int BK, int MODE>
__launch_bounds__(256)
__global__ void gemm_slab(const unsigned short* __restrict__ in,
                          const unsigned short* __restrict__ wn,
                          const float* __restrict__ bias,
                          unsigned short* __restrict__ outb,
                          float* __restrict__ outf) {
    constexpr int BKP = BK + 8;
    constexpr int CPT = CIN / BK;
    constexpr int NC  = NTAP * CPT;
    constexpr int KTOT = NTAP * CIN;
    __shared__ __align__(16) unsigned short As[128 * 72];   // sized for epilogue reuse
    __shared__ __align__(16) unsigned short Bs[64 * BKP];
    const int tid = threadIdx.x;
    const size_t b0 = blockIdx.x * 128;
    const int n0 = blockIdx.y * 64;
    const int l  = blockIdx.z;
    const int w = tid >> 6, lane = tid & 63, quad = lane >> 4, m16 = lane & 15;
    const int wm = w >> 1, wq = w & 1;
    const int mbase = wm * 64, nbase = wq * 32;
    floatx4 acc[4][2] = {};

    for (int ch = 0; ch < NC; ++ch) {
        int t = ch / CPT, inner = ch % CPT;
        int pos = STRIDE * l + t - PAD;
        if (pos < 0 || pos >= LIN) continue;
        const unsigned short* ag = in + ((size_t)pos * BATCH + b0) * CIN + inner * BK;
        for (int u = tid; u < 128 * (BK / 8); u += 256) {
            int r = u / (BK / 8), cc = u % (BK / 8);
            *(short8v*)&As[r * BKP + cc * 8] = *(const short8v*)&ag[(size_t)r * CIN + cc * 8];
        }
        const unsigned short* bg = wn + (size_t)n0 * KTOT + t * CIN + inner * BK;
        for (int u = tid; u < 64 * (BK / 8); u += 256) {
            int r = u / (BK / 8), cc = u % (BK / 8);
            *(short8v*)&Bs[r * BKP + cc * 8] = *(const short8v*)&bg[(size_t)r * KTOT + cc * 8];
        }
        __syncthreads();
#pragma unroll
        for (int kk = 0; kk < BK; kk += 32) {
            short8v bfr[2];
#pragma unroll
            for (int fn = 0; fn < 2; fn++)
                bfr[fn] = *(short8v*)&Bs[(nbase + fn * 16 + m16) * BKP + kk + quad * 8];
#pragma unroll
            for (int fm = 0; fm < 4; fm++) {
                short8v afr = *(short8v*)&As[(mbase + fm * 16 + m16) * BKP + kk + quad * 8];
                acc[fm][0] = __builtin_amdgcn_mfma_f32_16x16x32_bf16(afr, bfr[0], acc[fm][0], 0, 0, 0);
                acc[fm][1] = __builtin_amdgcn_mfma_f32_16x16x32_bf16(afr, bfr[1], acc[fm][1], 0, 0, 0);
            }
        }
        __syncthreads();
    }

    // ---- epilogue ----
    if constexpr (MODE == 4) {
        int c0g = n0 + nbase + m16, c1g = c0g + 16;
        float bv0 = (c0g < 210) ? bias[c0g] : 0.f;
        float bv1 = (c1g < 210) ? bias[c1g] : 0.f;
#pragma unroll
        for (int fm = 0; fm < 4; fm++)
#pragma unroll
            for (int r = 0; r < 4; r++) {
                size_t row = b0 + mbase + fm * 16 + quad * 4 + r;
                if (c0g < 210) outf[row * 210 + c0g] = acc[fm][0][r] + bv0;
                if (c1g < 210) outf[row * 210 + c1g] = acc[fm][1][r] + bv1;
            }
    } else {
        float bv0 = bias[n0 + nbase + m16], bv1 = bias[n0 + nbase + 16 + m16];
        if constexpr (MODE == 2) {
#pragma unroll
            for (int fm = 0; fm < 4; fm++)
#pragma unroll
                for (int r = 0; r < 4; r++) {
                    size_t row = b0 + mbase + fm * 16 + quad * 4 + r;
                    outf[row * 128 + n0 + nbase + m16]      = acc[fm][0][r] + bv0;
                    outf[row * 128 + n0 + nbase + 16 + m16] = acc[fm][1][r] + bv1;
                }
        }
        unsigned short* Cs = As;   // reuse staging LDS (all mfma complete)
#pragma unroll
        for (int fm = 0; fm < 4; fm++)
#pragma unroll
            for (int r = 0; r < 4; r++) {
                int row = mbase + fm * 16 + quad * 4 + r;
                Cs[row * 72 + nbase + m16]      = f2b(fmaxf(acc[fm][0][r] + bv0, 0.f));
                Cs[row * 72 + nbase + 16 + m16] = f2b(fmaxf(acc[fm][1][r] + bv1, 0.f));
            }
        __syncthreads();
        for (int u = tid; u < 1024; u += 256) {
            int r = u >> 3, cc = u & 7;
            *(short8v*)&outb[((size_t)l * BATCH + b0 + r) * NOUT + n0 + cc * 8] =
                *(short8v*)&Cs[r * 72 + cc * 8];
        }
    }
}

// ---------------------------------------------------------------------------
extern "C" void kernel_launch(void* const* d_in, const int* in_sizes, int n_in,
                              void* d_out, int out_size, void* d_ws, size_t ws_size,
                              hipStream_t stream) {
    const float* src  = (const float*)d_in[0];
    const int*   eidx = (const int*)  d_in[1];
    const float* g1w  = (const float*)d_in[2];
    const float* g1b  = (const float*)d_in[3];
    const float* g2w  = (const float*)d_in[4];
    const float* g2b  = (const float*)d_in[5];
    const float* cv1w = (const float*)d_in[6];
    const float* cv1b = (const float*)d_in[7];
    const float* cv2w = (const float*)d_in[8];
    const float* cv2b = (const float*)d_in[9];
    const float* cv3w = (const float*)d_in[10];
    const float* cv3b = (const float*)d_in[11];
    const float* fc1w = (const float*)d_in[12];
    const float* fc1b = (const float*)d_in[13];
    const float* cl1w = (const float*)d_in[14];
    const float* cl1b = (const float*)d_in[15];
    const float* cl2w = (const float*)d_in[16];
    const float* cl2b = (const float*)d_in[17];

    unsigned short* ws16 = (unsigned short*)d_ws;
    int*   wsI = (int*)d_ws;
    float* wsF = (float*)d_ws;
    float* out = (float*)d_out;

    unsigned short* xa  = ws16 + R0_OFF;
    unsigned short* hw2 = ws16 + R1_OFF;
    unsigned short* h2  = ws16 + R0_OFF;
    unsigned short* c1  = ws16 + R1_OFF;
    unsigned short* c2  = ws16 + R0_OFF;
    unsigned short* c3  = ws16 + R1_OFF;
    unsigned short* fr  = ws16 + FR_OFF;
    unsigned short* r2  = ws16 + R2_OFF;
    unsigned short* w1n = ws16 + W1N_OFF;
    unsigned short* w2n = ws16 + W2N_OFF;
    unsigned short* wc1 = ws16 + WC1_OFF;
    unsigned short* wc2 = ws16 + WC2_OFF;
    unsigned short* wc3 = ws16 + WC3_OFF;
    unsigned short* wf1 = ws16 + WF1_OFF;
    unsigned short* wl1 = ws16 + WL1_OFF;
    unsigned short* wl2 = ws16 + WL2_OFF;
    int*   gptr  = wsI + PTR_I;
    int*   gcols = wsI + COLS_I;
    float* gnrm  = wsF + NRM_I;

    float* feat_out = out + 8192ull * 210ull;

    prep_edges<<<1, 256, 0, stream>>>(eidx, gptr, gcols, gnrm);
    prep_weights<<<2345, 256, 0, stream>>>(g1w, g2w, cv1w, cv2w, cv3w, fc1w, cl1w, cl2w,
                                           ws16 + WT_OFF);
    trans_agg1<<<1024, 256, 0, stream>>>(src, gptr, gcols, gnrm, xa);
    gcn12<<<dim3(64, 1, 96), 256, 0, stream>>>(xa, w1n, w2n, g1b, hw2);
    agg2<<<dim3(96, 8), 256, 0, stream>>>(hw2, gptr, gcols, gnrm, g2b, h2);
    gemm_slab<7, 32, 64, 2, 3, 96, 32, 0>
        <<<dim3(64, 1, 48), 256, 0, stream>>>(h2, wc1, cv1b, c1, nullptr);
    gemm_slab<5, 64, 128, 2, 2, 48, 64, 0>
        <<<dim3(64, 2, 24), 256, 0, stream>>>(c1, wc2, cv2b, c2, nullptr);
    gemm_slab<3, 128, 256, 2, 1, 24, 64, 0>
        <<<dim3(64, 4, 12), 256, 0, stream>>>(c2, wc3, cv3b, c3, nullptr);
    gemm_slab<12, 256, 128, 1, 0, 12, 64, 2>
        <<<dim3(64, 2, 1), 256, 0, stream>>>(c3, wf1, fc1b, fr, feat_out);
    gemm_slab<1, 128, 128, 1, 0, 1, 64, 0>
        <<<dim3(64, 2, 1), 256, 0, stream>>>(fr, wl1, cl1b, r2, nullptr);
    gemm_slab<1, 128, 256, 1, 0, 1, 64, 4>
        <<<dim3(64, 4, 1), 256, 0, stream>>>(r2, wl2, cl2b, nullptr, out);
}

// Round 4
// 524.038 us; speedup vs baseline: 3.6040x; 1.1636x over previous
//
#include <hip/hip_runtime.h>

// ---------------------------------------------------------------------------
// TimeSeriesGCN — bf16 MFMA pipeline, batch-as-M GEMMs on position-major slabs.
// trans_agg1:  src -> xa[96][8192][32]   (AhatX, ch16..31 zero)
// gcn12:       xa -> hw2[96][8192][32]
// agg2:        hw2 -> h2[96][8192][32]
// conv1/2/3:   slab GEMMs -> c1[48][8192][64], c2[24][8192][128], c3[12][8192][256]
// fc1_splitk:  c3 -> fp32 partials (6-way split-K, in dead c2 region)
// fc1_reduce:  partials -> feat (fp32 d_out) + fr (bf16 relu)
// cls1 (WM=2): fr -> r2; cls2 (WM=2): r2 -> logits (fp32 d_out)
// ---------------------------------------------------------------------------

typedef __attribute__((ext_vector_type(8))) short short8v;
typedef __attribute__((ext_vector_type(4))) float floatx4;

#define N_NODE 96
#define E_TOT  864
#define BATCH  8192ull

// ws layout, ushort elements
#define R0_OFF   0ull
#define R1_OFF   25165824ull
#define FR_OFF   50331648ull
#define R2_OFF   51380224ull
#define WT_OFF   52428800ull
#define W1N_OFF  (WT_OFF + 0)
#define W2N_OFF  (WT_OFF + 2048)
#define WC1_OFF  (WT_OFF + 4096)
#define WC2_OFF  (WT_OFF + 18432)
#define WC3_OFF  (WT_OFF + 59392)
#define WF1_OFF  (WT_OFF + 157696)
#define WL1_OFF  (WT_OFF + 550912)
#define WL2_OFF  (WT_OFF + 567296)
// CSR, int elements from (int*)d_ws
#define PTR_I    26514432ull
#define COLS_I   26514560ull
#define NRM_I    26515456ull

__device__ __forceinline__ unsigned short f2b(float f) {
    unsigned int u = __builtin_bit_cast(unsigned int, f);
    u += 0x7fffu + ((u >> 16) & 1u);
    return (unsigned short)(u >> 16);
}
__device__ __forceinline__ float b2f(unsigned short h) {
    unsigned int u = ((unsigned int)h) << 16;
    return __builtin_bit_cast(float, u);
}

// ---------------------------------------------------------------------------
__global__ void prep_edges(const int* __restrict__ eidx, int* __restrict__ gptr,
                           int* __restrict__ gcols, float* __restrict__ gnrm) {
    __shared__ int rowv[E_TOT];
    __shared__ int colv[E_TOT];
    __shared__ int degi[N_NODE];
    __shared__ int ptr_s[N_NODE + 1];
    __shared__ float dinv[N_NODE];
    const int tid = threadIdx.x;
    for (int e = tid; e < E_TOT; e += 256) {
        int r, c;
        if (e < 768) { r = eidx[e]; c = eidx[768 + e]; }
        else         { r = e - 768; c = r; }
        rowv[e] = r; colv[e] = c;
    }
    for (int n = tid; n < N_NODE; n += 256) degi[n] = 0;
    __syncthreads();
    for (int e = tid; e < E_TOT; e += 256) atomicAdd(&degi[rowv[e]], 1);
    __syncthreads();
    for (int n = tid; n < N_NODE; n += 256)
        dinv[n] = rsqrtf(fmaxf((float)degi[n], 1e-12f));
    if (tid == 0) {
        ptr_s[0] = 0;
        for (int n = 0; n < N_NODE; n++) ptr_s[n + 1] = ptr_s[n] + degi[n];
    }
    __syncthreads();
    if (tid <= N_NODE) gptr[tid] = ptr_s[tid];
    if (tid < N_NODE) {
        int wp = ptr_s[tid];
        for (int e = 0; e < E_TOT; e++) {
            if (rowv[e] == tid) {
                gcols[wp] = colv[e];
                gnrm[wp]  = dinv[tid] * dinv[colv[e]];
                wp++;
            }
        }
    }
}

// ---------------------------------------------------------------------------
__global__ void prep_weights(const float* __restrict__ g1w, const float* __restrict__ g2w,
                             const float* __restrict__ w1, const float* __restrict__ w2,
                             const float* __restrict__ w3, const float* __restrict__ f1,
                             const float* __restrict__ l1, const float* __restrict__ l2,
                             unsigned short* __restrict__ wt) {
    long idx = (long)blockIdx.x * 256 + threadIdx.x;
    if (idx >= 600064) return;
    float v;
    if (idx < 2048) {
        int o = idx >> 5, c = idx & 31;
        v = (c < 16) ? g1w[c * 64 + o] : 0.f;
    } else if (idx < 4096) {
        long j = idx - 2048; int g = j >> 6, c = j & 63;
        v = g2w[c * 32 + g];
    } else if (idx < 18432) {
        long j = idx - 4096; int o = j / 224, m = j % 224, t = m >> 5, c = m & 31;
        v = w1[o * 224 + c * 7 + t];
    } else if (idx < 59392) {
        long j = idx - 18432; int o = j / 320, m = j % 320, t = m >> 6, c = m & 63;
        v = w2[o * 320 + c * 5 + t];
    } else if (idx < 157696) {
        long j = idx - 59392; int o = j / 384, m = j % 384, t = m >> 7, c = m & 127;
        v = w3[o * 384 + c * 3 + t];
    } else if (idx < 550912) {
        long j = idx - 157696; int f = j / 3072, m = j % 3072, t = m >> 8, o = m & 255;
        v = f1[(o * 12 + t) * 128 + f];
    } else if (idx < 567296) {
        long j = idx - 550912; int f2 = j >> 7, ff = j & 127;
        v = l1[ff * 128 + f2];
    } else {
        long j = idx - 567296; int n = j >> 7, f = j & 127;
        v = (n < 210) ? l2[f * 210 + n] : 0.f;
    }
    wt[idx] = f2b(v);
}

// ---------------------------------------------------------------------------
__launch_bounds__(256)
__global__ void trans_agg1(const float* __restrict__ src,
                           const int* __restrict__ gptr, const int* __restrict__ gcols,
                           const float* __restrict__ gnrm, unsigned short* __restrict__ xa) {
    __shared__ __align__(16) float xs[8 * 1544];
    __shared__ int ptr_s[97];
    __shared__ int cols_s[E_TOT];
    __shared__ float nrm_s[E_TOT];
    const int tid = threadIdx.x;
    const int b0 = blockIdx.x * 8;
    if (tid < 97) ptr_s[tid] = gptr[tid];
    for (int i = tid; i < E_TOT; i += 256) { cols_s[i] = gcols[i]; nrm_s[i] = gnrm[i]; }
    for (int u = tid; u < 3072; u += 256) {
        int bl = u / 384, j = u % 384;
        float4 v = *(const float4*)&src[((size_t)(b0 + bl)) * 1536 + j * 4];
        *(float4*)&xs[bl * 1544 + j * 4] = v;
    }
    __syncthreads();
    for (int u = tid; u < 768; u += 256) {
        int n = u >> 3, bl = u & 7;
        float a[16];
#pragma unroll
        for (int c = 0; c < 16; c++) a[c] = 0.f;
        int e0 = ptr_s[n], e1 = ptr_s[n + 1];
        for (int j = e0; j < e1; j++) {
            int s = cols_s[j]; float wv = nrm_s[j];
            const float* base = &xs[bl * 1544 + s];
#pragma unroll
            for (int c = 0; c < 16; c++) a[c] += wv * base[c * 96];
        }
        unsigned int d[8];
#pragma unroll
        for (int c2 = 0; c2 < 8; c2++)
            d[c2] = (unsigned int)f2b(a[2 * c2]) | ((unsigned int)f2b(a[2 * c2 + 1]) << 16);
        unsigned int* o = (unsigned int*)(xa + ((size_t)n * BATCH + b0 + bl) * 32);
        *(uint4*)&o[0] = make_uint4(d[0], d[1], d[2], d[3]);
        *(uint4*)&o[4] = make_uint4(d[4], d[5], d[6], d[7]);
        *(uint4*)&o[8]  = make_uint4(0, 0, 0, 0);
        *(uint4*)&o[12] = make_uint4(0, 0, 0, 0);
    }
}

// ---------------------------------------------------------------------------
__launch_bounds__(256)
__global__ void gcn12(const unsigned short* __restrict__ xa,
                      const unsigned short* __restrict__ w1n,
                      const unsigned short* __restrict__ w2n,
                      const float* __restrict__ b1, unsigned short* __restrict__ hw2) {
    __shared__ __align__(16) unsigned short As[128 * 40];
    __shared__ __align__(16) unsigned short B1s[64 * 40];
    __shared__ __align__(16) unsigned short H1s[128 * 72];
    __shared__ __align__(16) unsigned short B2s[32 * 72];
    const int tid = threadIdx.x;
    const size_t b0 = blockIdx.x * 128;
    const int l = blockIdx.z;
    const int w = tid >> 6, lane = tid & 63, quad = lane >> 4, m16 = lane & 15;

    for (int u = tid; u < 512; u += 256) {
        int r = u >> 2, cc = u & 3;
        *(short8v*)&As[r * 40 + cc * 8] =
            *(const short8v*)&xa[((size_t)l * BATCH + b0 + r) * 32 + cc * 8];
    }
    for (int u = tid; u < 256; u += 256) {
        int r = u >> 2, cc = u & 3;
        *(short8v*)&B1s[r * 40 + cc * 8] = *(const short8v*)&w1n[r * 32 + cc * 8];
    }
    for (int u = tid; u < 256; u += 256) {
        int r = u >> 3, cc = u & 7;
        *(short8v*)&B2s[r * 72 + cc * 8] = *(const short8v*)&w2n[r * 64 + cc * 8];
    }
    __syncthreads();

    {
        const int wm = w >> 1, wq = w & 1;
        const int mbase = wm * 64, nbase = wq * 32;
        floatx4 acc[4][2] = {};
#pragma unroll
        for (int fn = 0; fn < 2; fn++) {
            short8v bfr = *(short8v*)&B1s[(nbase + fn * 16 + m16) * 40 + quad * 8];
#pragma unroll
            for (int fm = 0; fm < 4; fm++) {
                short8v afr = *(short8v*)&As[(mbase + fm * 16 + m16) * 40 + quad * 8];
                acc[fm][fn] = __builtin_amdgcn_mfma_f32_16x16x32_bf16(afr, bfr, acc[fm][fn], 0, 0, 0);
            }
        }
        float bv0 = b1[nbase + m16], bv1 = b1[nbase + 16 + m16];
#pragma unroll
        for (int fm = 0; fm < 4; fm++)
#pragma unroll
            for (int r = 0; r < 4; r++) {
                int row = mbase + fm * 16 + quad * 4 + r;
                H1s[row * 72 + nbase + m16]      = f2b(fmaxf(acc[fm][0][r] + bv0, 0.f));
                H1s[row * 72 + nbase + 16 + m16] = f2b(fmaxf(acc[fm][1][r] + bv1, 0.f));
            }
    }
    __syncthreads();

    {
        const int mb2 = w * 32;
        floatx4 acc[2][2] = {};
#pragma unroll
        for (int kk = 0; kk < 64; kk += 32)
#pragma unroll
            for (int fn = 0; fn < 2; fn++) {
                short8v bfr = *(short8v*)&B2s[(fn * 16 + m16) * 72 + kk + quad * 8];
#pragma unroll
                for (int fm = 0; fm < 2; fm++) {
                    short8v afr = *(short8v*)&H1s[(mb2 + fm * 16 + m16) * 72 + kk + quad * 8];
                    acc[fm][fn] = __builtin_amdgcn_mfma_f32_16x16x32_bf16(afr, bfr, acc[fm][fn], 0, 0, 0);
                }
            }
        unsigned short* Cs = As;
#pragma unroll
        for (int fm = 0; fm < 2; fm++)
#pragma unroll
            for (int r = 0; r < 4; r++) {
                int row = mb2 + fm * 16 + quad * 4 + r;
                Cs[row * 40 + m16]      = f2b(acc[fm][0][r]);
                Cs[row * 40 + 16 + m16] = f2b(acc[fm][1][r]);
            }
    }
    __syncthreads();
    for (int u = tid; u < 512; u += 256) {
        int r = u >> 2, cc = u & 3;
        *(short8v*)&hw2[((size_t)l * BATCH + b0 + r) * 32 + cc * 8] =
            *(short8v*)&As[r * 40 + cc * 8];
    }
}

// ---------------------------------------------------------------------------
__launch_bounds__(256)
__global__ void agg2(const unsigned short* __restrict__ hw2,
                     const int* __restrict__ gptr, const int* __restrict__ gcols,
                     const float* __restrict__ gnrm, const float* __restrict__ b2,
                     unsigned short* __restrict__ h2) {
    __shared__ int cols_s[E_TOT];
    __shared__ float nrm_s[E_TOT];
    __shared__ int e0s, e1s;
    const int tid = threadIdx.x;
    const int n = blockIdx.x;
    const size_t b0 = (size_t)blockIdx.y * 1024;
    if (tid == 0) { e0s = gptr[n]; e1s = gptr[n + 1]; }
    for (int i = tid; i < E_TOT; i += 256) { cols_s[i] = gcols[i]; nrm_s[i] = gnrm[i]; }
    __syncthreads();
    const int e0 = e0s, e1 = e1s;
    float bias[8];
    for (int u = tid; u < 4096; u += 256) {
        int bl = u >> 2, cc = u & 3;
#pragma unroll
        for (int i = 0; i < 8; i++) bias[i] = b2[cc * 8 + i];
        float a[8];
#pragma unroll
        for (int i = 0; i < 8; i++) a[i] = bias[i];
        for (int j = e0; j < e1; j++) {
            size_t s = (size_t)cols_s[j];
            float wv = nrm_s[j];
            uint4 g = *(const uint4*)&hw2[(s * BATCH + b0 + bl) * 32 + cc * 8];
            unsigned int gg[4] = {g.x, g.y, g.z, g.w};
#pragma unroll
            for (int p = 0; p < 4; p++) {
                a[2 * p]     += wv * b2f((unsigned short)(gg[p] & 0xffff));
                a[2 * p + 1] += wv * b2f((unsigned short)(gg[p] >> 16));
            }
        }
        unsigned int d[4];
#pragma unroll
        for (int p = 0; p < 4; p++)
            d[p] = (unsigned int)f2b(fmaxf(a[2 * p], 0.f)) |
                   ((unsigned int)f2b(fmaxf(a[2 * p + 1], 0.f)) << 16);
        *(uint4*)&h2[((size_t)n * BATCH + b0 + bl) * 32 + cc * 8] =
            make_uint4(d[0], d[1], d[2], d[3]);
    }
}

// ---------------------------------------------------------------------------
// Unified slab GEMM. WM = m-frags per wave (BM = WM*32). BN=64, 4 waves 2x2.
// MODE 0: bf16 out + bias + relu. MODE 4: cls2 fp32 out [210-stride], masked.
// ---------------------------------------------------------------------------
template<int WM, int NTAP, int CIN, int NOUT, int STRIDE, int PAD, int LIN, int BK, int MODE>
__launch_bounds__(256)
__global__ void gemm_slab(const unsigned short* __restrict__ in,
                          const unsigned short* __restrict__ wn,
                          const float* __restrict__ bias,
                          unsigned short* __restrict__ outb,
                          float* __restrict__ outf) {
    constexpr int BM  = WM * 32;
    constexpr int BKP = BK + 8;
    constexpr int CPT = CIN / BK;
    constexpr int NC  = NTAP * CPT;
    constexpr int KTOT = NTAP * CIN;
    __shared__ __align__(16) unsigned short As[BM * 72];
    __shared__ __align__(16) unsigned short Bs[64 * BKP];
    const int tid = threadIdx.x;
    const size_t b0 = blockIdx.x * BM;
    const int n0 = blockIdx.y * 64;
    const int l  = blockIdx.z;
    const int w = tid >> 6, lane = tid & 63, quad = lane >> 4, m16 = lane & 15;
    const int wm = w >> 1, wq = w & 1;
    const int mbase = wm * (WM * 16), nbase = wq * 32;
    floatx4 acc[WM][2] = {};

    for (int ch = 0; ch < NC; ++ch) {
        int t = ch / CPT, inner = ch % CPT;
        int pos = STRIDE * l + t - PAD;
        if (pos < 0 || pos >= LIN) continue;
        const unsigned short* ag = in + ((size_t)pos * BATCH + b0) * CIN + inner * BK;
        for (int u = tid; u < BM * (BK / 8); u += 256) {
            int r = u / (BK / 8), cc = u % (BK / 8);
            *(short8v*)&As[r * BKP + cc * 8] = *(const short8v*)&ag[(size_t)r * CIN + cc * 8];
        }
        const unsigned short* bg = wn + (size_t)n0 * KTOT + t * CIN + inner * BK;
        for (int u = tid; u < 64 * (BK / 8); u += 256) {
            int r = u / (BK / 8), cc = u % (BK / 8);
            *(short8v*)&Bs[r * BKP + cc * 8] = *(const short8v*)&bg[(size_t)r * KTOT + cc * 8];
        }
        __syncthreads();
#pragma unroll
        for (int kk = 0; kk < BK; kk += 32) {
            short8v bfr[2];
#pragma unroll
            for (int fn = 0; fn < 2; fn++)
                bfr[fn] = *(short8v*)&Bs[(nbase + fn * 16 + m16) * BKP + kk + quad * 8];
#pragma unroll
            for (int fm = 0; fm < WM; fm++) {
                short8v afr = *(short8v*)&As[(mbase + fm * 16 + m16) * BKP + kk + quad * 8];
                acc[fm][0] = __builtin_amdgcn_mfma_f32_16x16x32_bf16(afr, bfr[0], acc[fm][0], 0, 0, 0);
                acc[fm][1] = __builtin_amdgcn_mfma_f32_16x16x32_bf16(afr, bfr[1], acc[fm][1], 0, 0, 0);
            }
        }
        __syncthreads();
    }

    if constexpr (MODE == 4) {
        int c0g = n0 + nbase + m16, c1g = c0g + 16;
        float bv0 = (c0g < 210) ? bias[c0g] : 0.f;
        float bv1 = (c1g < 210) ? bias[c1g] : 0.f;
#pragma unroll
        for (int fm = 0; fm < WM; fm++)
#pragma unroll
            for (int r = 0; r < 4; r++) {
                size_t row = b0 + mbase + fm * 16 + quad * 4 + r;
                if (c0g < 210) outf[row * 210 + c0g] = acc[fm][0][r] + bv0;
                if (c1g < 210) outf[row * 210 + c1g] = acc[fm][1][r] + bv1;
            }
    } else {
        float bv0 = bias[n0 + nbase + m16], bv1 = bias[n0 + nbase + 16 + m16];
        unsigned short* Cs = As;
#pragma unroll
        for (int fm = 0; fm < WM; fm++)
#pragma unroll
            for (int r = 0; r < 4; r++) {
                int row = mbase + fm * 16 + quad * 4 + r;
                Cs[row * 72 + nbase + m16]      = f2b(fmaxf(acc[fm][0][r] + bv0, 0.f));
                Cs[row * 72 + nbase + 16 + m16] = f2b(fmaxf(acc[fm][1][r] + bv1, 0.f));
            }
        __syncthreads();
        for (int u = tid; u < BM * 8; u += 256) {
            int r = u >> 3, cc = u & 7;
            *(short8v*)&outb[((size_t)l * BATCH + b0 + r) * NOUT + n0 + cc * 8] =
                *(short8v*)&Cs[r * 72 + cc * 8];
        }
    }
}

// ---------------------------------------------------------------------------
// fc1 split-K: grid (64, 2, 6). z handles taps {2z, 2z+1} (K=512, BK=64).
// Writes fp32 partials part[z][8192][128] (region = dead c2 slab).
// ---------------------------------------------------------------------------
__launch_bounds__(256)
__global__ void fc1_splitk(const unsigned short* __restrict__ c3,
                           const unsigned short* __restrict__ wf1,
                           float* __restrict__ part) {
    __shared__ __align__(16) unsigned short As[128 * 72];
    __shared__ __align__(16) unsigned short Bs[64 * 72];
    const int tid = threadIdx.x;
    const size_t b0 = blockIdx.x * 128;
    const int n0 = blockIdx.y * 64;
    const int kg = blockIdx.z;
    const int w = tid >> 6, lane = tid & 63, quad = lane >> 4, m16 = lane & 15;
    const int wm = w >> 1, wq = w & 1;
    const int mbase = wm * 64, nbase = wq * 32;
    floatx4 acc[4][2] = {};

#pragma unroll
    for (int tt = 0; tt < 2; tt++) {
        const int t = kg * 2 + tt;
#pragma unroll
        for (int inner = 0; inner < 4; inner++) {
            const unsigned short* ag = c3 + ((size_t)t * BATCH + b0) * 256 + inner * 64;
            for (int u = tid; u < 1024; u += 256) {
                int r = u >> 3, cc = u & 7;
                *(short8v*)&As[r * 72 + cc * 8] = *(const short8v*)&ag[(size_t)r * 256 + cc * 8];
            }
            const unsigned short* bg = wf1 + (size_t)n0 * 3072 + t * 256 + inner * 64;
            for (int u = tid; u < 512; u += 256) {
                int r = u >> 3, cc = u & 7;
                *(short8v*)&Bs[r * 72 + cc * 8] = *(const short8v*)&bg[(size_t)r * 3072 + cc * 8];
            }
            __syncthreads();
#pragma unroll
            for (int kk = 0; kk < 64; kk += 32) {
                short8v bfr[2];
#pragma unroll
                for (int fn = 0; fn < 2; fn++)
                    bfr[fn] = *(short8v*)&Bs[(nbase + fn * 16 + m16) * 72 + kk + quad * 8];
#pragma unroll
                for (int fm = 0; fm < 4; fm++) {
                    short8v afr = *(short8v*)&As[(mbase + fm * 16 + m16) * 72 + kk + quad * 8];
                    acc[fm][0] = __builtin_amdgcn_mfma_f32_16x16x32_bf16(afr, bfr[0], acc[fm][0], 0, 0, 0);
                    acc[fm][1] = __builtin_amdgcn_mfma_f32_16x16x32_bf16(afr, bfr[1], acc[fm][1], 0, 0, 0);
                }
            }
            __syncthreads();
        }
    }
    float* pg = part + (size_t)kg * BATCH * 128;
#pragma unroll
    for (int fm = 0; fm < 4; fm++)
#pragma unroll
        for (int r = 0; r < 4; r++) {
            size_t row = b0 + mbase + fm * 16 + quad * 4 + r;
            pg[row * 128 + n0 + nbase + m16]      = acc[fm][0][r];
            pg[row * 128 + n0 + nbase + 16 + m16] = acc[fm][1][r];
        }
}

// ---------------------------------------------------------------------------
// fc1_reduce: feat = sum_z part + bias (fp32 to d_out), fr = bf16(relu(feat)).
// 1024 blocks x 256 threads, one float4 per thread.
// ---------------------------------------------------------------------------
__launch_bounds__(256)
__global__ void fc1_reduce(const float* __restrict__ part, const float* __restrict__ bias,
                           float* __restrict__ feat, unsigned short* __restrict__ fr) {
    const size_t idx = (size_t)blockIdx.x * 256 + threadIdx.x;   // quad index
    const size_t row = idx >> 5;
    const int    c4  = (int)(idx & 31);
    float4 s = *(const float4*)&bias[c4 * 4];
#pragma unroll
    for (int z = 0; z < 6; z++) {
        float4 p = *(const float4*)&part[(z * BATCH + row) * 128 + c4 * 4];
        s.x += p.x; s.y += p.y; s.z += p.z; s.w += p.w;
    }
    *(float4*)&feat[row * 128 + c4 * 4] = s;
    unsigned int d0 = (unsigned int)f2b(fmaxf(s.x, 0.f)) |
                      ((unsigned int)f2b(fmaxf(s.y, 0.f)) << 16);
    unsigned int d1 = (unsigned int)f2b(fmaxf(s.z, 0.f)) |
                      ((unsigned int)f2b(fmaxf(s.w, 0.f)) << 16);
    *(uint2*)&fr[row * 128 + c4 * 4] = make_uint2(d0, d1);
}

// ---------------------------------------------------------------------------
extern "C" void kernel_launch(void* const* d_in, const int* in_sizes, int n_in,
                              void* d_out, int out_size, void* d_ws, size_t ws_size,
                              hipStream_t stream) {
    const float* src  = (const float*)d_in[0];
    const int*   eidx = (const int*)  d_in[1];
    const float* g1w  = (const float*)d_in[2];
    const float* g1b  = (const float*)d_in[3];
    const float* g2w  = (const float*)d_in[4];
    const float* g2b  = (const float*)d_in[5];
    const float* cv1w = (const float*)d_in[6];
    const float* cv1b = (const float*)d_in[7];
    const float* cv2w = (const float*)d_in[8];
    const float* cv2b = (const float*)d_in[9];
    const float* cv3w = (const float*)d_in[10];
    const float* cv3b = (const float*)d_in[11];
    const float* fc1w = (const float*)d_in[12];
    const float* fc1b = (const float*)d_in[13];
    const float* cl1w = (const float*)d_in[14];
    const float* cl1b = (const float*)d_in[15];
    const float* cl2w = (const float*)d_in[16];
    const float* cl2b = (const float*)d_in[17];

    unsigned short* ws16 = (unsigned short*)d_ws;
    int*   wsI = (int*)d_ws;
    float* wsF = (float*)d_ws;
    float* out = (float*)d_out;

    unsigned short* xa  = ws16 + R0_OFF;
    unsigned short* hw2 = ws16 + R1_OFF;
    unsigned short* h2  = ws16 + R0_OFF;
    unsigned short* c1  = ws16 + R1_OFF;
    unsigned short* c2  = ws16 + R0_OFF;
    unsigned short* c3  = ws16 + R1_OFF;
    float*          part = wsF;              // aliases dead c2 (R0), 25 MB
    unsigned short* fr  = ws16 + FR_OFF;
    unsigned short* r2  = ws16 + R2_OFF;
    unsigned short* w1n = ws16 + W1N_OFF;
    unsigned short* w2n = ws16 + W2N_OFF;
    unsigned short* wc1 = ws16 + WC1_OFF;
    unsigned short* wc2 = ws16 + WC2_OFF;
    unsigned short* wc3 = ws16 + WC3_OFF;
    unsigned short* wf1 = ws16 + WF1_OFF;
    unsigned short* wl1 = ws16 + WL1_OFF;
    unsigned short* wl2 = ws16 + WL2_OFF;
    int*   gptr  = wsI + PTR_I;
    int*   gcols = wsI + COLS_I;
    float* gnrm  = wsF + NRM_I;

    float* feat_out = out + 8192ull * 210ull;

    prep_edges<<<1, 256, 0, stream>>>(eidx, gptr, gcols, gnrm);
    prep_weights<<<2345, 256, 0, stream>>>(g1w, g2w, cv1w, cv2w, cv3w, fc1w, cl1w, cl2w,
                                           ws16 + WT_OFF);
    trans_agg1<<<1024, 256, 0, stream>>>(src, gptr, gcols, gnrm, xa);
    gcn12<<<dim3(64, 1, 96), 256, 0, stream>>>(xa, w1n, w2n, g1b, hw2);
    agg2<<<dim3(96, 8), 256, 0, stream>>>(hw2, gptr, gcols, gnrm, g2b, h2);
    gemm_slab<4, 7, 32, 64, 2, 3, 96, 32, 0>
        <<<dim3(64, 1, 48), 256, 0, stream>>>(h2, wc1, cv1b, c1, nullptr);
    gemm_slab<4, 5, 64, 128, 2, 2, 48, 64, 0>
        <<<dim3(64, 2, 24), 256, 0, stream>>>(c1, wc2, cv2b, c2, nullptr);
    gemm_slab<4, 3, 128, 256, 2, 1, 24, 64, 0>
        <<<dim3(64, 4, 12), 256, 0, stream>>>(c2, wc3, cv3b, c3, nullptr);
    fc1_splitk<<<dim3(64, 2, 6), 256, 0, stream>>>(c3, wf1, part);
    fc1_reduce<<<1024, 256, 0, stream>>>(part, fc1b, feat_out, fr);
    gemm_slab<2, 1, 128, 128, 1, 0, 1, 64, 0>
        <<<dim3(128, 2, 1), 256, 0, stream>>>(fr, wl1, cl1b, r2, nullptr);
    gemm_slab<2, 1, 128, 256, 1, 0, 1, 64, 4>
        <<<dim3(128, 4, 1), 256, 0, stream>>>(r2, wl2, cl2b, nullptr, out);
}

// Round 5
// 515.582 us; speedup vs baseline: 3.6631x; 1.0164x over previous
//
#include <hip/hip_runtime.h>

// ---------------------------------------------------------------------------
// TimeSeriesGCN — bf16 MFMA pipeline, batch-as-M GEMMs on position-major slabs.
// trans_agg1:  src -> xa[96][8192][32]   (AhatX, ch16..31 zero)
// gcn12:       xa -> hw2[96][8192][32]
// agg2:        hw2 -> h2[96][8192][32]   (batch-chunk blocks, graph in LDS)
// conv1/2/3:   slab GEMMs -> c1[48][8192][64], c2[24][8192][128], c3[12][8192][256]
// fc1_splitk:  c3 -> fp32 partials (6-way split-K, BN=128, in dead c2 region)
// fc1_reduce:  partials -> feat (fp32 d_out) + fr (bf16 relu)
// cls1 (WM=2): fr -> r2; cls2 (WM=2): r2 -> logits (fp32 d_out)
// ---------------------------------------------------------------------------

typedef __attribute__((ext_vector_type(8))) short short8v;
typedef __attribute__((ext_vector_type(4))) float floatx4;

#define N_NODE 96
#define E_TOT  864
#define BATCH  8192ull

// ws layout, ushort elements
#define R0_OFF   0ull
#define R1_OFF   25165824ull
#define FR_OFF   50331648ull
#define R2_OFF   51380224ull
#define WT_OFF   52428800ull
#define W1N_OFF  (WT_OFF + 0)
#define W2N_OFF  (WT_OFF + 2048)
#define WC1_OFF  (WT_OFF + 4096)
#define WC2_OFF  (WT_OFF + 18432)
#define WC3_OFF  (WT_OFF + 59392)
#define WF1_OFF  (WT_OFF + 157696)
#define WL1_OFF  (WT_OFF + 550912)
#define WL2_OFF  (WT_OFF + 567296)
// CSR, int elements from (int*)d_ws
#define PTR_I    26514432ull
#define COLS_I   26514560ull
#define NRM_I    26515456ull

__device__ __forceinline__ unsigned short f2b(float f) {
    unsigned int u = __builtin_bit_cast(unsigned int, f);
    u += 0x7fffu + ((u >> 16) & 1u);
    return (unsigned short)(u >> 16);
}
__device__ __forceinline__ float b2f(unsigned short h) {
    unsigned int u = ((unsigned int)h) << 16;
    return __builtin_bit_cast(float, u);
}

// ---------------------------------------------------------------------------
__global__ void prep_edges(const int* __restrict__ eidx, int* __restrict__ gptr,
                           int* __restrict__ gcols, float* __restrict__ gnrm) {
    __shared__ int rowv[E_TOT];
    __shared__ int colv[E_TOT];
    __shared__ int degi[N_NODE];
    __shared__ int ptr_s[N_NODE + 1];
    __shared__ float dinv[N_NODE];
    const int tid = threadIdx.x;
    for (int e = tid; e < E_TOT; e += 256) {
        int r, c;
        if (e < 768) { r = eidx[e]; c = eidx[768 + e]; }
        else         { r = e - 768; c = r; }
        rowv[e] = r; colv[e] = c;
    }
    for (int n = tid; n < N_NODE; n += 256) degi[n] = 0;
    __syncthreads();
    for (int e = tid; e < E_TOT; e += 256) atomicAdd(&degi[rowv[e]], 1);
    __syncthreads();
    for (int n = tid; n < N_NODE; n += 256)
        dinv[n] = rsqrtf(fmaxf((float)degi[n], 1e-12f));
    if (tid == 0) {
        ptr_s[0] = 0;
        for (int n = 0; n < N_NODE; n++) ptr_s[n + 1] = ptr_s[n] + degi[n];
    }
    __syncthreads();
    if (tid <= N_NODE) gptr[tid] = ptr_s[tid];
    if (tid < N_NODE) {
        int wp = ptr_s[tid];
        for (int e = 0; e < E_TOT; e++) {
            if (rowv[e] == tid) {
                gcols[wp] = colv[e];
                gnrm[wp]  = dinv[tid] * dinv[colv[e]];
                wp++;
            }
        }
    }
}

// ---------------------------------------------------------------------------
__global__ void prep_weights(const float* __restrict__ g1w, const float* __restrict__ g2w,
                             const float* __restrict__ w1, const float* __restrict__ w2,
                             const float* __restrict__ w3, const float* __restrict__ f1,
                             const float* __restrict__ l1, const float* __restrict__ l2,
                             unsigned short* __restrict__ wt) {
    long idx = (long)blockIdx.x * 256 + threadIdx.x;
    if (idx >= 600064) return;
    float v;
    if (idx < 2048) {
        int o = idx >> 5, c = idx & 31;
        v = (c < 16) ? g1w[c * 64 + o] : 0.f;
    } else if (idx < 4096) {
        long j = idx - 2048; int g = j >> 6, c = j & 63;
        v = g2w[c * 32 + g];
    } else if (idx < 18432) {
        long j = idx - 4096; int o = j / 224, m = j % 224, t = m >> 5, c = m & 31;
        v = w1[o * 224 + c * 7 + t];
    } else if (idx < 59392) {
        long j = idx - 18432; int o = j / 320, m = j % 320, t = m >> 6, c = m & 63;
        v = w2[o * 320 + c * 5 + t];
    } else if (idx < 157696) {
        long j = idx - 59392; int o = j / 384, m = j % 384, t = m >> 7, c = m & 127;
        v = w3[o * 384 + c * 3 + t];
    } else if (idx < 550912) {
        long j = idx - 157696; int f = j / 3072, m = j % 3072, t = m >> 8, o = m & 255;
        v = f1[(o * 12 + t) * 128 + f];
    } else if (idx < 567296) {
        long j = idx - 550912; int f2 = j >> 7, ff = j & 127;
        v = l1[ff * 128 + f2];
    } else {
        long j = idx - 567296; int n = j >> 7, f = j & 127;
        v = (n < 210) ? l2[f * 210 + n] : 0.f;
    }
    wt[idx] = f2b(v);
}

// ---------------------------------------------------------------------------
__launch_bounds__(256)
__global__ void trans_agg1(const float* __restrict__ src,
                           const int* __restrict__ gptr, const int* __restrict__ gcols,
                           const float* __restrict__ gnrm, unsigned short* __restrict__ xa) {
    __shared__ __align__(16) float xs[8 * 1544];
    __shared__ int ptr_s[97];
    __shared__ int cols_s[E_TOT];
    __shared__ float nrm_s[E_TOT];
    const int tid = threadIdx.x;
    const int b0 = blockIdx.x * 8;
    if (tid < 97) ptr_s[tid] = gptr[tid];
    for (int i = tid; i < E_TOT; i += 256) { cols_s[i] = gcols[i]; nrm_s[i] = gnrm[i]; }
    for (int u = tid; u < 3072; u += 256) {
        int bl = u / 384, j = u % 384;
        float4 v = *(const float4*)&src[((size_t)(b0 + bl)) * 1536 + j * 4];
        *(float4*)&xs[bl * 1544 + j * 4] = v;
    }
    __syncthreads();
    for (int u = tid; u < 768; u += 256) {
        int n = u >> 3, bl = u & 7;
        float a[16];
#pragma unroll
        for (int c = 0; c < 16; c++) a[c] = 0.f;
        int e0 = ptr_s[n], e1 = ptr_s[n + 1];
        for (int j = e0; j < e1; j++) {
            int s = cols_s[j]; float wv = nrm_s[j];
            const float* base = &xs[bl * 1544 + s];
#pragma unroll
            for (int c = 0; c < 16; c++) a[c] += wv * base[c * 96];
        }
        unsigned int d[8];
#pragma unroll
        for (int c2 = 0; c2 < 8; c2++)
            d[c2] = (unsigned int)f2b(a[2 * c2]) | ((unsigned int)f2b(a[2 * c2 + 1]) << 16);
        unsigned int* o = (unsigned int*)(xa + ((size_t)n * BATCH + b0 + bl) * 32);
        *(uint4*)&o[0] = make_uint4(d[0], d[1], d[2], d[3]);
        *(uint4*)&o[4] = make_uint4(d[4], d[5], d[6], d[7]);
        *(uint4*)&o[8]  = make_uint4(0, 0, 0, 0);
        *(uint4*)&o[12] = make_uint4(0, 0, 0, 0);
    }
}

// ---------------------------------------------------------------------------
__launch_bounds__(256)
__global__ void gcn12(const unsigned short* __restrict__ xa,
                      const unsigned short* __restrict__ w1n,
                      const unsigned short* __restrict__ w2n,
                      const float* __restrict__ b1, unsigned short* __restrict__ hw2) {
    __shared__ __align__(16) unsigned short As[128 * 40];
    __shared__ __align__(16) unsigned short B1s[64 * 40];
    __shared__ __align__(16) unsigned short H1s[128 * 72];
    __shared__ __align__(16) unsigned short B2s[32 * 72];
    const int tid = threadIdx.x;
    const size_t b0 = blockIdx.x * 128;
    const int l = blockIdx.z;
    const int w = tid >> 6, lane = tid & 63, quad = lane >> 4, m16 = lane & 15;

    for (int u = tid; u < 512; u += 256) {
        int r = u >> 2, cc = u & 3;
        *(short8v*)&As[r * 40 + cc * 8] =
            *(const short8v*)&xa[((size_t)l * BATCH + b0 + r) * 32 + cc * 8];
    }
    for (int u = tid; u < 256; u += 256) {
        int r = u >> 2, cc = u & 3;
        *(short8v*)&B1s[r * 40 + cc * 8] = *(const short8v*)&w1n[r * 32 + cc * 8];
    }
    for (int u = tid; u < 256; u += 256) {
        int r = u >> 3, cc = u & 7;
        *(short8v*)&B2s[r * 72 + cc * 8] = *(const short8v*)&w2n[r * 64 + cc * 8];
    }
    __syncthreads();

    {
        const int wm = w >> 1, wq = w & 1;
        const int mbase = wm * 64, nbase = wq * 32;
        floatx4 acc[4][2] = {};
#pragma unroll
        for (int fn = 0; fn < 2; fn++) {
            short8v bfr = *(short8v*)&B1s[(nbase + fn * 16 + m16) * 40 + quad * 8];
#pragma unroll
            for (int fm = 0; fm < 4; fm++) {
                short8v afr = *(short8v*)&As[(mbase + fm * 16 + m16) * 40 + quad * 8];
                acc[fm][fn] = __builtin_amdgcn_mfma_f32_16x16x32_bf16(afr, bfr, acc[fm][fn], 0, 0, 0);
            }
        }
        float bv0 = b1[nbase + m16], bv1 = b1[nbase + 16 + m16];
#pragma unroll
        for (int fm = 0; fm < 4; fm++)
#pragma unroll
            for (int r = 0; r < 4; r++) {
                int row = mbase + fm * 16 + quad * 4 + r;
                H1s[row * 72 + nbase + m16]      = f2b(fmaxf(acc[fm][0][r] + bv0, 0.f));
                H1s[row * 72 + nbase + 16 + m16] = f2b(fmaxf(acc[fm][1][r] + bv1, 0.f));
            }
    }
    __syncthreads();

    {
        const int mb2 = w * 32;
        floatx4 acc[2][2] = {};
#pragma unroll
        for (int kk = 0; kk < 64; kk += 32)
#pragma unroll
            for (int fn = 0; fn < 2; fn++) {
                short8v bfr = *(short8v*)&B2s[(fn * 16 + m16) * 72 + kk + quad * 8];
#pragma unroll
                for (int fm = 0; fm < 2; fm++) {
                    short8v afr = *(short8v*)&H1s[(mb2 + fm * 16 + m16) * 72 + kk + quad * 8];
                    acc[fm][fn] = __builtin_amdgcn_mfma_f32_16x16x32_bf16(afr, bfr, acc[fm][fn], 0, 0, 0);
                }
            }
        unsigned short* Cs = As;
#pragma unroll
        for (int fm = 0; fm < 2; fm++)
#pragma unroll
            for (int r = 0; r < 4; r++) {
                int row = mb2 + fm * 16 + quad * 4 + r;
                Cs[row * 40 + m16]      = f2b(acc[fm][0][r]);
                Cs[row * 40 + 16 + m16] = f2b(acc[fm][1][r]);
            }
    }
    __syncthreads();
    for (int u = tid; u < 512; u += 256) {
        int r = u >> 2, cc = u & 3;
        *(short8v*)&hw2[((size_t)l * BATCH + b0 + r) * 32 + cc * 8] =
            *(short8v*)&As[r * 40 + cc * 8];
    }
}

// ---------------------------------------------------------------------------
// agg2 v2: one block per 8-row batch chunk; ALL 96 node slabs in LDS (48 KB).
// Each hw2 byte fetched from HBM exactly once. grid 1024 blocks.
// ---------------------------------------------------------------------------
__launch_bounds__(256)
__global__ void agg2(const unsigned short* __restrict__ hw2,
                     const int* __restrict__ gptr, const int* __restrict__ gcols,
                     const float* __restrict__ gnrm, const float* __restrict__ b2,
                     unsigned short* __restrict__ h2) {
    __shared__ __align__(16) unsigned int hin[96 * 128];   // [n][bl*16+gpair] dwords
    __shared__ int ptr_s[97];
    __shared__ int cols_s[E_TOT];
    __shared__ float nrm_s[E_TOT];
    __shared__ float b2s[32];
    const int tid = threadIdx.x;
    const size_t b0 = (size_t)blockIdx.x * 8;
    if (tid < 97) ptr_s[tid] = gptr[tid];
    if (tid < 32) b2s[tid] = b2[tid];
    for (int i = tid; i < E_TOT; i += 256) { cols_s[i] = gcols[i]; nrm_s[i] = gnrm[i]; }
    // stage: per node n, rows b0..b0+7 are 512 contiguous bytes
    for (int u = tid; u < 3072; u += 256) {
        int n = u >> 5, q = u & 31;      // q: uint4 within the 512B chunk
        *(uint4*)&hin[n * 128 + q * 4] =
            *(const uint4*)&hw2[((size_t)n * BATCH + b0) * 32 + q * 8];
    }
    __syncthreads();
    // compute: 96*8*16 dword outputs; wave-uniform n (u%128 spans bl,gpair)
    for (int u = tid; u < 12288; u += 256) {
        int n = u >> 7, r = u & 127, bl = r >> 4, gp = r & 15;
        const int e0 = ptr_s[n], e1 = ptr_s[n + 1];
        float a0 = b2s[gp * 2], a1 = b2s[gp * 2 + 1];
        for (int j = e0; j < e1; j++) {
            unsigned int d = hin[cols_s[j] * 128 + r];
            float wv = nrm_s[j];
            a0 += wv * b2f((unsigned short)(d & 0xffff));
            a1 += wv * b2f((unsigned short)(d >> 16));
        }
        unsigned int o = (unsigned int)f2b(fmaxf(a0, 0.f)) |
                         ((unsigned int)f2b(fmaxf(a1, 0.f)) << 16);
        ((unsigned int*)h2)[((size_t)n * BATCH + b0 + bl) * 16 + gp] = o;
    }
}

// ---------------------------------------------------------------------------
// Unified slab GEMM. WM = m-frags per wave (BM = WM*32). BN=64, 4 waves 2x2.
// MODE 0: bf16 out + bias + relu. MODE 4: cls2 fp32 out [210-stride], masked.
// ---------------------------------------------------------------------------
template<int WM, int NTAP, int CIN, int NOUT, int STRIDE, int PAD, int LIN, int BK, int MODE>
__launch_bounds__(256)
__global__ void gemm_slab(const unsigned short* __restrict__ in,
                          const unsigned short* __restrict__ wn,
                          const float* __restrict__ bias,
                          unsigned short* __restrict__ outb,
                          float* __restrict__ outf) {
    constexpr int BM  = WM * 32;
    constexpr int BKP = BK + 8;
    constexpr int CPT = CIN / BK;
    constexpr int NC  = NTAP * CPT;
    constexpr int KTOT = NTAP * CIN;
    __shared__ __align__(16) unsigned short As[BM * 72];
    __shared__ __align__(16) unsigned short Bs[64 * BKP];
    const int tid = threadIdx.x;
    const size_t b0 = blockIdx.x * BM;
    const int n0 = blockIdx.y * 64;
    const int l  = blockIdx.z;
    const int w = tid >> 6, lane = tid & 63, quad = lane >> 4, m16 = lane & 15;
    const int wm = w >> 1, wq = w & 1;
    const int mbase = wm * (WM * 16), nbase = wq * 32;
    floatx4 acc[WM][2] = {};

    for (int ch = 0; ch < NC; ++ch) {
        int t = ch / CPT, inner = ch % CPT;
        int pos = STRIDE * l + t - PAD;
        if (pos < 0 || pos >= LIN) continue;
        const unsigned short* ag = in + ((size_t)pos * BATCH + b0) * CIN + inner * BK;
        for (int u = tid; u < BM * (BK / 8); u += 256) {
            int r = u / (BK / 8), cc = u % (BK / 8);
            *(short8v*)&As[r * BKP + cc * 8] = *(const short8v*)&ag[(size_t)r * CIN + cc * 8];
        }
        const unsigned short* bg = wn + (size_t)n0 * KTOT + t * CIN + inner * BK;
        for (int u = tid; u < 64 * (BK / 8); u += 256) {
            int r = u / (BK / 8), cc = u % (BK / 8);
            *(short8v*)&Bs[r * BKP + cc * 8] = *(const short8v*)&bg[(size_t)r * KTOT + cc * 8];
        }
        __syncthreads();
#pragma unroll
        for (int kk = 0; kk < BK; kk += 32) {
            short8v bfr[2];
#pragma unroll
            for (int fn = 0; fn < 2; fn++)
                bfr[fn] = *(short8v*)&Bs[(nbase + fn * 16 + m16) * BKP + kk + quad * 8];
#pragma unroll
            for (int fm = 0; fm < WM; fm++) {
                short8v afr = *(short8v*)&As[(mbase + fm * 16 + m16) * BKP + kk + quad * 8];
                acc[fm][0] = __builtin_amdgcn_mfma_f32_16x16x32_bf16(afr, bfr[0], acc[fm][0], 0, 0, 0);
                acc[fm][1] = __builtin_amdgcn_mfma_f32_16x16x32_bf16(afr, bfr[1], acc[fm][1], 0, 0, 0);
            }
        }
        __syncthreads();
    }

    if constexpr (MODE == 4) {
        int c0g = n0 + nbase + m16, c1g = c0g + 16;
        float bv0 = (c0g < 210) ? bias[c0g] : 0.f;
        float bv1 = (c1g < 210) ? bias[c1g] : 0.f;
#pragma unroll
        for (int fm = 0; fm < WM; fm++)
#pragma unroll
            for (int r = 0; r < 4; r++) {
                size_t row = b0 + mbase + fm * 16 + quad * 4 + r;
                if (c0g < 210) outf[row * 210 + c0g] = acc[fm][0][r] + bv0;
                if (c1g < 210) outf[row * 210 + c1g] = acc[fm][1][r] + bv1;
            }
    } else {
        float bv0 = bias[n0 + nbase + m16], bv1 = bias[n0 + nbase + 16 + m16];
        unsigned short* Cs = As;
#pragma unroll
        for (int fm = 0; fm < WM; fm++)
#pragma unroll
            for (int r = 0; r < 4; r++) {
                int row = mbase + fm * 16 + quad * 4 + r;
                Cs[row * 72 + nbase + m16]      = f2b(fmaxf(acc[fm][0][r] + bv0, 0.f));
                Cs[row * 72 + nbase + 16 + m16] = f2b(fmaxf(acc[fm][1][r] + bv1, 0.f));
            }
        __syncthreads();
        for (int u = tid; u < BM * 8; u += 256) {
            int r = u >> 3, cc = u & 7;
            *(short8v*)&outb[((size_t)l * BATCH + b0 + r) * NOUT + n0 + cc * 8] =
                *(short8v*)&Cs[r * 72 + cc * 8];
        }
    }
}

// ---------------------------------------------------------------------------
// fc1 split-K v2: BN=128 (no y-split, A read once). grid (64, 1, 6).
// Waves 2x2, each 64x64: WM=4, FN=4. Partials part[z][8192][128] fp32.
// ---------------------------------------------------------------------------
__launch_bounds__(256)
__global__ void fc1_splitk(const unsigned short* __restrict__ c3,
                           const unsigned short* __restrict__ wf1,
                           float* __restrict__ part) {
    __shared__ __align__(16) unsigned short As[128 * 72];
    __shared__ __align__(16) unsigned short Bs[128 * 72];
    const int tid = threadIdx.x;
    const size_t b0 = blockIdx.x * 128;
    const int kg = blockIdx.z;
    const int w = tid >> 6, lane = tid & 63, quad = lane >> 4, m16 = lane & 15;
    const int wm = w >> 1, wq = w & 1;
    const int mbase = wm * 64, nbase = wq * 64;
    floatx4 acc[4][4] = {};

#pragma unroll
    for (int tt = 0; tt < 2; tt++) {
        const int t = kg * 2 + tt;
#pragma unroll
        for (int inner = 0; inner < 4; inner++) {
            const unsigned short* ag = c3 + ((size_t)t * BATCH + b0) * 256 + inner * 64;
            for (int u = tid; u < 1024; u += 256) {
                int r = u >> 3, cc = u & 7;
                *(short8v*)&As[r * 72 + cc * 8] = *(const short8v*)&ag[(size_t)r * 256 + cc * 8];
            }
            const unsigned short* bg = wf1 + t * 256 + inner * 64;
            for (int u = tid; u < 1024; u += 256) {
                int r = u >> 3, cc = u & 7;
                *(short8v*)&Bs[r * 72 + cc * 8] = *(const short8v*)&bg[(size_t)r * 3072 + cc * 8];
            }
            __syncthreads();
#pragma unroll
            for (int kk = 0; kk < 64; kk += 32) {
                short8v bfr[4];
#pragma unroll
                for (int fn = 0; fn < 4; fn++)
                    bfr[fn] = *(short8v*)&Bs[(nbase + fn * 16 + m16) * 72 + kk + quad * 8];
#pragma unroll
                for (int fm = 0; fm < 4; fm++) {
                    short8v afr = *(short8v*)&As[(mbase + fm * 16 + m16) * 72 + kk + quad * 8];
#pragma unroll
                    for (int fn = 0; fn < 4; fn++)
                        acc[fm][fn] = __builtin_amdgcn_mfma_f32_16x16x32_bf16(afr, bfr[fn], acc[fm][fn], 0, 0, 0);
                }
            }
            __syncthreads();
        }
    }
    float* pg = part + (size_t)kg * BATCH * 128;
#pragma unroll
    for (int fm = 0; fm < 4; fm++)
#pragma unroll
        for (int r = 0; r < 4; r++) {
            size_t row = b0 + mbase + fm * 16 + quad * 4 + r;
#pragma unroll
            for (int fn = 0; fn < 4; fn++)
                pg[row * 128 + nbase + fn * 16 + m16] = acc[fm][fn][r];
        }
}

// ---------------------------------------------------------------------------
__launch_bounds__(256)
__global__ void fc1_reduce(const float* __restrict__ part, const float* __restrict__ bias,
                           float* __restrict__ feat, unsigned short* __restrict__ fr) {
    const size_t idx = (size_t)blockIdx.x * 256 + threadIdx.x;   // quad index
    const size_t row = idx >> 5;
    const int    c4  = (int)(idx & 31);
    float4 s = *(const float4*)&bias[c4 * 4];
#pragma unroll
    for (int z = 0; z < 6; z++) {
        float4 p = *(const float4*)&part[(z * BATCH + row) * 128 + c4 * 4];
        s.x += p.x; s.y += p.y; s.z += p.z; s.w += p.w;
    }
    *(float4*)&feat[row * 128 + c4 * 4] = s;
    unsigned int d0 = (unsigned int)f2b(fmaxf(s.x, 0.f)) |
                      ((unsigned int)f2b(fmaxf(s.y, 0.f)) << 16);
    unsigned int d1 = (unsigned int)f2b(fmaxf(s.z, 0.f)) |
                      ((unsigned int)f2b(fmaxf(s.w, 0.f)) << 16);
    *(uint2*)&fr[row * 128 + c4 * 4] = make_uint2(d0, d1);
}

// ---------------------------------------------------------------------------
extern "C" void kernel_launch(void* const* d_in, const int* in_sizes, int n_in,
                              void* d_out, int out_size, void* d_ws, size_t ws_size,
                              hipStream_t stream) {
    const float* src  = (const float*)d_in[0];
    const int*   eidx = (const int*)  d_in[1];
    const float* g1w  = (const float*)d_in[2];
    const float* g1b  = (const float*)d_in[3];
    const float* g2w  = (const float*)d_in[4];
    const float* g2b  = (const float*)d_in[5];
    const float* cv1w = (const float*)d_in[6];
    const float* cv1b = (const float*)d_in[7];
    const float* cv2w = (const float*)d_in[8];
    const float* cv2b = (const float*)d_in[9];
    const float* cv3w = (const float*)d_in[10];
    const float* cv3b = (const float*)d_in[11];
    const float* fc1w = (const float*)d_in[12];
    const float* fc1b = (const float*)d_in[13];
    const float* cl1w = (const float*)d_in[14];
    const float* cl1b = (const float*)d_in[15];
    const float* cl2w = (const float*)d_in[16];
    const float* cl2b = (const float*)d_in[17];

    unsigned short* ws16 = (unsigned short*)d_ws;
    int*   wsI = (int*)d_ws;
    float* wsF = (float*)d_ws;
    float* out = (float*)d_out;

    unsigned short* xa  = ws16 + R0_OFF;
    unsigned short* hw2 = ws16 + R1_OFF;
    unsigned short* h2  = ws16 + R0_OFF;
    unsigned short* c1  = ws16 + R1_OFF;
    unsigned short* c2  = ws16 + R0_OFF;
    unsigned short* c3  = ws16 + R1_OFF;
    float*          part = wsF;              // aliases dead c2 (R0), 25 MB
    unsigned short* fr  = ws16 + FR_OFF;
    unsigned short* r2  = ws16 + R2_OFF;
    unsigned short* w1n = ws16 + W1N_OFF;
    unsigned short* w2n = ws16 + W2N_OFF;
    unsigned short* wc1 = ws16 + WC1_OFF;
    unsigned short* wc2 = ws16 + WC2_OFF;
    unsigned short* wc3 = ws16 + WC3_OFF;
    unsigned short* wf1 = ws16 + WF1_OFF;
    unsigned short* wl1 = ws16 + WL1_OFF;
    unsigned short* wl2 = ws16 + WL2_OFF;
    int*   gptr  = wsI + PTR_I;
    int*   gcols = wsI + COLS_I;
    float* gnrm  = wsF + NRM_I;

    float* feat_out = out + 8192ull * 210ull;

    prep_edges<<<1, 256, 0, stream>>>(eidx, gptr, gcols, gnrm);
    prep_weights<<<2345, 256, 0, stream>>>(g1w, g2w, cv1w, cv2w, cv3w, fc1w, cl1w, cl2w,
                                           ws16 + WT_OFF);
    trans_agg1<<<1024, 256, 0, stream>>>(src, gptr, gcols, gnrm, xa);
    gcn12<<<dim3(64, 1, 96), 256, 0, stream>>>(xa, w1n, w2n, g1b, hw2);
    agg2<<<1024, 256, 0, stream>>>(hw2, gptr, gcols, gnrm, g2b, h2);
    gemm_slab<4, 7, 32, 64, 2, 3, 96, 32, 0>
        <<<dim3(64, 1, 48), 256, 0, stream>>>(h2, wc1, cv1b, c1, nullptr);
    gemm_slab<4, 5, 64, 128, 2, 2, 48, 64, 0>
        <<<dim3(64, 2, 24), 256, 0, stream>>>(c1, wc2, cv2b, c2, nullptr);
    gemm_slab<4, 3, 128, 256, 2, 1, 24, 64, 0>
        <<<dim3(64, 4, 12), 256, 0, stream>>>(c2, wc3, cv3b, c3, nullptr);
    fc1_splitk<<<dim3(64, 1, 6), 256, 0, stream>>>(c3, wf1, part);
    fc1_reduce<<<1024, 256, 0, stream>>>(part, fc1b, feat_out, fr);
    gemm_slab<2, 1, 128, 128, 1, 0, 1, 64, 0>
        <<<dim3(128, 2, 1), 256, 0, stream>>>(fr, wl1, cl1b, r2, nullptr);
    gemm_slab<2, 1, 128, 256, 1, 0, 1, 64, 4>
        <<<dim3(128, 4, 1), 256, 0, stream>>>(r2, wl2, cl2b, nullptr, out);
}

// Round 6
// 367.376 us; speedup vs baseline: 5.1408x; 1.4034x over previous
//
#include <hip/hip_runtime.h>

// ---------------------------------------------------------------------------
// TimeSeriesGCN — bf16 MFMA pipeline, batch-as-M GEMMs on position-major slabs.
// prep_edges:  edge_index -> dense bf16 Ahat[96][96]
// trans16:     src -> xt[96][8192][16] (bf16 transpose only)
// agg_mm<16>:  xt -> xa = Ahat @ xt            (dense-GEMM aggregation)
// gcn12:       xa(16ch) -> hw2[96][8192][32]
// agg_mm<32>:  hw2 -> h2 = relu(Ahat @ hw2 + b2)
// conv1/2/3:   slab GEMMs -> c1[48][8192][64], c2[24][8192][128], c3[12][8192][256]
// fc1_splitk:  c3 -> fp32 partials (6-way split-K, BN=128)
// fc1_reduce:  partials -> feat (fp32 d_out) + fr (bf16 relu)
// cls1 (WM=2): fr -> r2; cls2 (WM=2): r2 -> logits (fp32 d_out)
// ---------------------------------------------------------------------------

typedef __attribute__((ext_vector_type(8))) short short8v;
typedef __attribute__((ext_vector_type(4))) float floatx4;

#define N_NODE 96
#define E_TOT  864
#define BATCH  8192ull

// ws layout, ushort elements
#define R0_OFF   0ull
#define R1_OFF   25165824ull
#define FR_OFF   50331648ull
#define R2_OFF   51380224ull
#define WT_OFF   52428800ull
#define W1N_OFF  (WT_OFF + 0)
#define W2N_OFF  (WT_OFF + 2048)
#define WC1_OFF  (WT_OFF + 4096)
#define WC2_OFF  (WT_OFF + 18432)
#define WC3_OFF  (WT_OFF + 59392)
#define WF1_OFF  (WT_OFF + 157696)
#define WL1_OFF  (WT_OFF + 550912)
#define WL2_OFF  (WT_OFF + 567296)
#define AH_OFF   (WT_OFF + 600064)   // dense Ahat bf16 [96][96]

__device__ __forceinline__ unsigned short f2b(float f) {
    unsigned int u = __builtin_bit_cast(unsigned int, f);
    u += 0x7fffu + ((u >> 16) & 1u);
    return (unsigned short)(u >> 16);
}
__device__ __forceinline__ float b2f(unsigned short h) {
    unsigned int u = ((unsigned int)h) << 16;
    return __builtin_bit_cast(float, u);
}

// ---------------------------------------------------------------------------
// Dense normalized adjacency: Ahat[n][s] = sum over edges(n,s) dinv[n]*dinv[s]
// (fp32 accumulate in LDS for multigraph duplicates, then one bf16 round).
// ---------------------------------------------------------------------------
__global__ void prep_edges(const int* __restrict__ eidx, unsigned short* __restrict__ adense) {
    __shared__ int rowv[E_TOT];
    __shared__ int colv[E_TOT];
    __shared__ int degi[N_NODE];
    __shared__ float dinv[N_NODE];
    __shared__ float ad[96 * 96];
    const int tid = threadIdx.x;
    for (int e = tid; e < E_TOT; e += 256) {
        int r, c;
        if (e < 768) { r = eidx[e]; c = eidx[768 + e]; }
        else         { r = e - 768; c = r; }
        rowv[e] = r; colv[e] = c;
    }
    for (int n = tid; n < N_NODE; n += 256) degi[n] = 0;
    for (int i = tid; i < 9216; i += 256) ad[i] = 0.f;
    __syncthreads();
    for (int e = tid; e < E_TOT; e += 256) atomicAdd(&degi[rowv[e]], 1);
    __syncthreads();
    for (int n = tid; n < N_NODE; n += 256)
        dinv[n] = rsqrtf(fmaxf((float)degi[n], 1e-12f));
    __syncthreads();
    for (int e = tid; e < E_TOT; e += 256)
        atomicAdd(&ad[rowv[e] * 96 + colv[e]], dinv[rowv[e]] * dinv[colv[e]]);
    __syncthreads();
    for (int i = tid; i < 9216; i += 256) adense[i] = f2b(ad[i]);
}

// ---------------------------------------------------------------------------
__global__ void prep_weights(const float* __restrict__ g1w, const float* __restrict__ g2w,
                             const float* __restrict__ w1, const float* __restrict__ w2,
                             const float* __restrict__ w3, const float* __restrict__ f1,
                             const float* __restrict__ l1, const float* __restrict__ l2,
                             unsigned short* __restrict__ wt) {
    long idx = (long)blockIdx.x * 256 + threadIdx.x;
    if (idx >= 600064) return;
    float v;
    if (idx < 2048) {
        int o = idx >> 5, c = idx & 31;
        v = (c < 16) ? g1w[c * 64 + o] : 0.f;
    } else if (idx < 4096) {
        long j = idx - 2048; int g = j >> 6, c = j & 63;
        v = g2w[c * 32 + g];
    } else if (idx < 18432) {
        long j = idx - 4096; int o = j / 224, m = j % 224, t = m >> 5, c = m & 31;
        v = w1[o * 224 + c * 7 + t];
    } else if (idx < 59392) {
        long j = idx - 18432; int o = j / 320, m = j % 320, t = m >> 6, c = m & 63;
        v = w2[o * 320 + c * 5 + t];
    } else if (idx < 157696) {
        long j = idx - 59392; int o = j / 384, m = j % 384, t = m >> 7, c = m & 127;
        v = w3[o * 384 + c * 3 + t];
    } else if (idx < 550912) {
        long j = idx - 157696; int f = j / 3072, m = j % 3072, t = m >> 8, o = m & 255;
        v = f1[(o * 12 + t) * 128 + f];
    } else if (idx < 567296) {
        long j = idx - 550912; int f2 = j >> 7, ff = j & 127;
        v = l1[ff * 128 + f2];
    } else {
        long j = idx - 567296; int n = j >> 7, f = j & 127;
        v = (n < 210) ? l2[f * 210 + n] : 0.f;
    }
    wt[idx] = f2b(v);
}

// ---------------------------------------------------------------------------
// trans16: src[b][c][n] fp32 -> xt[n][b][c] bf16 (16 ch). 1024 blocks.
// ---------------------------------------------------------------------------
__launch_bounds__(256)
__global__ void trans16(const float* __restrict__ src, unsigned short* __restrict__ xt) {
    __shared__ __align__(16) float xs[8 * 1544];
    const int tid = threadIdx.x;
    const int b0 = blockIdx.x * 8;
    for (int u = tid; u < 3072; u += 256) {
        int bl = u / 384, j = u % 384;
        *(float4*)&xs[bl * 1544 + j * 4] =
            *(const float4*)&src[((size_t)(b0 + bl)) * 1536 + j * 4];
    }
    __syncthreads();
    for (int u = tid; u < 768; u += 256) {
        int n = u >> 3, bl = u & 7;
        const float* base = &xs[bl * 1544 + n];
        unsigned int d[8];
#pragma unroll
        for (int c2 = 0; c2 < 8; c2++)
            d[c2] = (unsigned int)f2b(base[(2 * c2) * 96]) |
                    ((unsigned int)f2b(base[(2 * c2 + 1) * 96]) << 16);
        unsigned int* o = (unsigned int*)(xt + ((size_t)n * BATCH + b0 + bl) * 16);
        *(uint4*)&o[0] = make_uint4(d[0], d[1], d[2], d[3]);
        *(uint4*)&o[4] = make_uint4(d[4], d[5], d[6], d[7]);
    }
}

// ---------------------------------------------------------------------------
// agg_mm: out[n][col] = (relu?)( sum_s Ahat[n][s] * in[s][col] (+ bias[col%CH]) )
// Dense GEMM: M=96, K=96, N=8192*CH. Block = 256-col tile; wave = 64 cols, M=96.
// A in LDS (row-major, stride 104), B tile in LDS natural layout (stride 264);
// B fragments gathered with 8x ds_read_u16 (k-strided).
// ---------------------------------------------------------------------------
template<int CH, bool RELU>
__launch_bounds__(256)
__global__ void agg_mm(const unsigned short* __restrict__ in,
                       const unsigned short* __restrict__ adense,
                       const float* __restrict__ bias,
                       unsigned short* __restrict__ outp) {
    const size_t NCOL = 8192ull * CH;
    __shared__ __align__(16) unsigned short Al[96 * 104];
    __shared__ __align__(16) unsigned short Bs[96 * 264];
    const int tid = threadIdx.x;
    const size_t c0 = (size_t)blockIdx.x * 256;
    const int w = tid >> 6, lane = tid & 63, quad = lane >> 4, m16 = lane & 15;

    for (int u = tid; u < 1152; u += 256) {          // A: 96 x 96 bf16
        int r = u / 12, q = u % 12;
        *(short8v*)&Al[r * 104 + q * 8] = *(const short8v*)&adense[r * 96 + q * 8];
    }
    for (int u = tid; u < 3072; u += 256) {          // B: 96 x 256
        int r = u >> 5, q = u & 31;
        *(uint4*)&Bs[r * 264 + q * 8] = *(const uint4*)&in[(size_t)r * NCOL + c0 + q * 8];
    }
    __syncthreads();

    floatx4 acc[6][4] = {};
    const int nb = w * 64;
#pragma unroll
    for (int kk = 0; kk < 96; kk += 32) {
        short8v bfr[4];
#pragma unroll
        for (int fn = 0; fn < 4; fn++) {
            const int col = nb + fn * 16 + m16;
#pragma unroll
            for (int j = 0; j < 8; j++)
                bfr[fn][j] = (short)Bs[(kk + quad * 8 + j) * 264 + col];
        }
#pragma unroll
        for (int fm = 0; fm < 6; fm++) {
            short8v afr = *(short8v*)&Al[(fm * 16 + m16) * 104 + kk + quad * 8];
#pragma unroll
            for (int fn = 0; fn < 4; fn++)
                acc[fm][fn] = __builtin_amdgcn_mfma_f32_16x16x32_bf16(afr, bfr[fn], acc[fm][fn], 0, 0, 0);
        }
    }

#pragma unroll
    for (int fm = 0; fm < 6; fm++) {
#pragma unroll
        for (int fn = 0; fn < 4; fn++) {
            const int col = nb + fn * 16 + m16;
            float bv = 0.f;
            if constexpr (RELU) bv = bias[col & (CH - 1)];
#pragma unroll
            for (int r = 0; r < 4; r++) {
                int node = fm * 16 + quad * 4 + r;
                float v = acc[fm][fn][r];
                if constexpr (RELU) v = fmaxf(v + bv, 0.f);
                outp[(size_t)node * NCOL + c0 + col] = f2b(v);
            }
        }
    }
}

// ---------------------------------------------------------------------------
// gcn12: hw2 = relu(xa W1 + b1) W2 per node slab. xa is 16-ch (zero-pad in LDS).
// ---------------------------------------------------------------------------
__launch_bounds__(256)
__global__ void gcn12(const unsigned short* __restrict__ xa,
                      const unsigned short* __restrict__ w1n,
                      const unsigned short* __restrict__ w2n,
                      const float* __restrict__ b1, unsigned short* __restrict__ hw2) {
    __shared__ __align__(16) unsigned short As[128 * 40];
    __shared__ __align__(16) unsigned short B1s[64 * 40];
    __shared__ __align__(16) unsigned short H1s[128 * 72];
    __shared__ __align__(16) unsigned short B2s[32 * 72];
    const int tid = threadIdx.x;
    const size_t b0 = blockIdx.x * 128;
    const int l = blockIdx.z;
    const int w = tid >> 6, lane = tid & 63, quad = lane >> 4, m16 = lane & 15;

    short8v zz = {0, 0, 0, 0, 0, 0, 0, 0};
    for (int u = tid; u < 512; u += 256) {       // 128 rows x 4 vec8 (ch>=16 zero)
        int r = u >> 2, cc = u & 3;
        *(short8v*)&As[r * 40 + cc * 8] = (cc < 2)
            ? *(const short8v*)&xa[((size_t)l * BATCH + b0 + r) * 16 + cc * 8]
            : zz;
    }
    for (int u = tid; u < 256; u += 256) {
        int r = u >> 2, cc = u & 3;
        *(short8v*)&B1s[r * 40 + cc * 8] = *(const short8v*)&w1n[r * 32 + cc * 8];
    }
    for (int u = tid; u < 256; u += 256) {
        int r = u >> 3, cc = u & 7;
        *(short8v*)&B2s[r * 72 + cc * 8] = *(const short8v*)&w2n[r * 64 + cc * 8];
    }
    __syncthreads();

    {
        const int wm = w >> 1, wq = w & 1;
        const int mbase = wm * 64, nbase = wq * 32;
        floatx4 acc[4][2] = {};
#pragma unroll
        for (int fn = 0; fn < 2; fn++) {
            short8v bfr = *(short8v*)&B1s[(nbase + fn * 16 + m16) * 40 + quad * 8];
#pragma unroll
            for (int fm = 0; fm < 4; fm++) {
                short8v afr = *(short8v*)&As[(mbase + fm * 16 + m16) * 40 + quad * 8];
                acc[fm][fn] = __builtin_amdgcn_mfma_f32_16x16x32_bf16(afr, bfr, acc[fm][fn], 0, 0, 0);
            }
        }
        float bv0 = b1[nbase + m16], bv1 = b1[nbase + 16 + m16];
#pragma unroll
        for (int fm = 0; fm < 4; fm++)
#pragma unroll
            for (int r = 0; r < 4; r++) {
                int row = mbase + fm * 16 + quad * 4 + r;
                H1s[row * 72 + nbase + m16]      = f2b(fmaxf(acc[fm][0][r] + bv0, 0.f));
                H1s[row * 72 + nbase + 16 + m16] = f2b(fmaxf(acc[fm][1][r] + bv1, 0.f));
            }
    }
    __syncthreads();

    {
        const int mb2 = w * 32;
        floatx4 acc[2][2] = {};
#pragma unroll
        for (int kk = 0; kk < 64; kk += 32)
#pragma unroll
            for (int fn = 0; fn < 2; fn++) {
                short8v bfr = *(short8v*)&B2s[(fn * 16 + m16) * 72 + kk + quad * 8];
#pragma unroll
                for (int fm = 0; fm < 2; fm++) {
                    short8v afr = *(short8v*)&H1s[(mb2 + fm * 16 + m16) * 72 + kk + quad * 8];
                    acc[fm][fn] = __builtin_amdgcn_mfma_f32_16x16x32_bf16(afr, bfr, acc[fm][fn], 0, 0, 0);
                }
            }
        unsigned short* Cs = As;
#pragma unroll
        for (int fm = 0; fm < 2; fm++)
#pragma unroll
            for (int r = 0; r < 4; r++) {
                int row = mb2 + fm * 16 + quad * 4 + r;
                Cs[row * 40 + m16]      = f2b(acc[fm][0][r]);
                Cs[row * 40 + 16 + m16] = f2b(acc[fm][1][r]);
            }
    }
    __syncthreads();
    for (int u = tid; u < 512; u += 256) {
        int r = u >> 2, cc = u & 3;
        *(short8v*)&hw2[((size_t)l * BATCH + b0 + r) * 32 + cc * 8] =
            *(short8v*)&As[r * 40 + cc * 8];
    }
}

// ---------------------------------------------------------------------------
// Unified slab GEMM. WM = m-frags per wave (BM = WM*32). BN=64, 4 waves 2x2.
// MODE 0: bf16 out + bias + relu. MODE 4: cls2 fp32 out [210-stride], masked.
// ---------------------------------------------------------------------------
template<int WM, int NTAP, int CIN, int NOUT, int STRIDE, int PAD, int LIN, int BK, int MODE>
__launch_bounds__(256)
__global__ void gemm_slab(const unsigned short* __restrict__ in,
                          const unsigned short* __restrict__ wn,
                          const float* __restrict__ bias,
                          unsigned short* __restrict__ outb,
                          float* __restrict__ outf) {
    constexpr int BM  = WM * 32;
    constexpr int BKP = BK + 8;
    constexpr int CPT = CIN / BK;
    constexpr int NC  = NTAP * CPT;
    constexpr int KTOT = NTAP * CIN;
    __shared__ __align__(16) unsigned short As[BM * 72];
    __shared__ __align__(16) unsigned short Bs[64 * BKP];
    const int tid = threadIdx.x;
    const size_t b0 = blockIdx.x * BM;
    const int n0 = blockIdx.y * 64;
    const int l  = blockIdx.z;
    const int w = tid >> 6, lane = tid & 63, quad = lane >> 4, m16 = lane & 15;
    const int wm = w >> 1, wq = w & 1;
    const int mbase = wm * (WM * 16), nbase = wq * 32;
    floatx4 acc[WM][2] = {};

    for (int ch = 0; ch < NC; ++ch) {
        int t = ch / CPT, inner = ch % CPT;
        int pos = STRIDE * l + t - PAD;
        if (pos < 0 || pos >= LIN) continue;
        const unsigned short* ag = in + ((size_t)pos * BATCH + b0) * CIN + inner * BK;
        for (int u = tid; u < BM * (BK / 8); u += 256) {
            int r = u / (BK / 8), cc = u % (BK / 8);
            *(short8v*)&As[r * BKP + cc * 8] = *(const short8v*)&ag[(size_t)r * CIN + cc * 8];
        }
        const unsigned short* bg = wn + (size_t)n0 * KTOT + t * CIN + inner * BK;
        for (int u = tid; u < 64 * (BK / 8); u += 256) {
            int r = u / (BK / 8), cc = u % (BK / 8);
            *(short8v*)&Bs[r * BKP + cc * 8] = *(const short8v*)&bg[(size_t)r * KTOT + cc * 8];
        }
        __syncthreads();
#pragma unroll
        for (int kk = 0; kk < BK; kk += 32) {
            short8v bfr[2];
#pragma unroll
            for (int fn = 0; fn < 2; fn++)
                bfr[fn] = *(short8v*)&Bs[(nbase + fn * 16 + m16) * BKP + kk + quad * 8];
#pragma unroll
            for (int fm = 0; fm < WM; fm++) {
                short8v afr = *(short8v*)&As[(mbase + fm * 16 + m16) * BKP + kk + quad * 8];
                acc[fm][0] = __builtin_amdgcn_mfma_f32_16x16x32_bf16(afr, bfr[0], acc[fm][0], 0, 0, 0);
                acc[fm][1] = __builtin_amdgcn_mfma_f32_16x16x32_bf16(afr, bfr[1], acc[fm][1], 0, 0, 0);
            }
        }
        __syncthreads();
    }

    if constexpr (MODE == 4) {
        int c0g = n0 + nbase + m16, c1g = c0g + 16;
        float bv0 = (c0g < 210) ? bias[c0g] : 0.f;
        float bv1 = (c1g < 210) ? bias[c1g] : 0.f;
#pragma unroll
        for (int fm = 0; fm < WM; fm++)
#pragma unroll
            for (int r = 0; r < 4; r++) {
                size_t row = b0 + mbase + fm * 16 + quad * 4 + r;
                if (c0g < 210) outf[row * 210 + c0g] = acc[fm][0][r] + bv0;
                if (c1g < 210) outf[row * 210 + c1g] = acc[fm][1][r] + bv1;
            }
    } else {
        float bv0 = bias[n0 + nbase + m16], bv1 = bias[n0 + nbase + 16 + m16];
        unsigned short* Cs = As;
#pragma unroll
        for (int fm = 0; fm < WM; fm++)
#pragma unroll
            for (int r = 0; r < 4; r++) {
                int row = mbase + fm * 16 + quad * 4 + r;
                Cs[row * 72 + nbase + m16]      = f2b(fmaxf(acc[fm][0][r] + bv0, 0.f));
                Cs[row * 72 + nbase + 16 + m16] = f2b(fmaxf(acc[fm][1][r] + bv1, 0.f));
            }
        __syncthreads();
        for (int u = tid; u < BM * 8; u += 256) {
            int r = u >> 3, cc = u & 7;
            *(short8v*)&outb[((size_t)l * BATCH + b0 + r) * NOUT + n0 + cc * 8] =
                *(short8v*)&Cs[r * 72 + cc * 8];
        }
    }
}

// ---------------------------------------------------------------------------
// fc1 split-K: BN=128 (A read once). grid (64, 1, 6). Waves 2x2, each 64x64.
// ---------------------------------------------------------------------------
__launch_bounds__(256)
__global__ void fc1_splitk(const unsigned short* __restrict__ c3,
                           const unsigned short* __restrict__ wf1,
                           float* __restrict__ part) {
    __shared__ __align__(16) unsigned short As[128 * 72];
    __shared__ __align__(16) unsigned short Bs[128 * 72];
    const int tid = threadIdx.x;
    const size_t b0 = blockIdx.x * 128;
    const int kg = blockIdx.z;
    const int w = tid >> 6, lane = tid & 63, quad = lane >> 4, m16 = lane & 15;
    const int wm = w >> 1, wq = w & 1;
    const int mbase = wm * 64, nbase = wq * 64;
    floatx4 acc[4][4] = {};

#pragma unroll
    for (int tt = 0; tt < 2; tt++) {
        const int t = kg * 2 + tt;
#pragma unroll
        for (int inner = 0; inner < 4; inner++) {
            const unsigned short* ag = c3 + ((size_t)t * BATCH + b0) * 256 + inner * 64;
            for (int u = tid; u < 1024; u += 256) {
                int r = u >> 3, cc = u & 7;
                *(short8v*)&As[r * 72 + cc * 8] = *(const short8v*)&ag[(size_t)r * 256 + cc * 8];
            }
            const unsigned short* bg = wf1 + t * 256 + inner * 64;
            for (int u = tid; u < 1024; u += 256) {
                int r = u >> 3, cc = u & 7;
                *(short8v*)&Bs[r * 72 + cc * 8] = *(const short8v*)&bg[(size_t)r * 3072 + cc * 8];
            }
            __syncthreads();
#pragma unroll
            for (int kk = 0; kk < 64; kk += 32) {
                short8v bfr[4];
#pragma unroll
                for (int fn = 0; fn < 4; fn++)
                    bfr[fn] = *(short8v*)&Bs[(nbase + fn * 16 + m16) * 72 + kk + quad * 8];
#pragma unroll
                for (int fm = 0; fm < 4; fm++) {
                    short8v afr = *(short8v*)&As[(mbase + fm * 16 + m16) * 72 + kk + quad * 8];
#pragma unroll
                    for (int fn = 0; fn < 4; fn++)
                        acc[fm][fn] = __builtin_amdgcn_mfma_f32_16x16x32_bf16(afr, bfr[fn], acc[fm][fn], 0, 0, 0);
                }
            }
            __syncthreads();
        }
    }
    float* pg = part + (size_t)kg * BATCH * 128;
#pragma unroll
    for (int fm = 0; fm < 4; fm++)
#pragma unroll
        for (int r = 0; r < 4; r++) {
            size_t row = b0 + mbase + fm * 16 + quad * 4 + r;
#pragma unroll
            for (int fn = 0; fn < 4; fn++)
                pg[row * 128 + nbase + fn * 16 + m16] = acc[fm][fn][r];
        }
}

// ---------------------------------------------------------------------------
__launch_bounds__(256)
__global__ void fc1_reduce(const float* __restrict__ part, const float* __restrict__ bias,
                           float* __restrict__ feat, unsigned short* __restrict__ fr) {
    const size_t idx = (size_t)blockIdx.x * 256 + threadIdx.x;
    const size_t row = idx >> 5;
    const int    c4  = (int)(idx & 31);
    float4 s = *(const float4*)&bias[c4 * 4];
#pragma unroll
    for (int z = 0; z < 6; z++) {
        float4 p = *(const float4*)&part[(z * BATCH + row) * 128 + c4 * 4];
        s.x += p.x; s.y += p.y; s.z += p.z; s.w += p.w;
    }
    *(float4*)&feat[row * 128 + c4 * 4] = s;
    unsigned int d0 = (unsigned int)f2b(fmaxf(s.x, 0.f)) |
                      ((unsigned int)f2b(fmaxf(s.y, 0.f)) << 16);
    unsigned int d1 = (unsigned int)f2b(fmaxf(s.z, 0.f)) |
                      ((unsigned int)f2b(fmaxf(s.w, 0.f)) << 16);
    *(uint2*)&fr[row * 128 + c4 * 4] = make_uint2(d0, d1);
}

// ---------------------------------------------------------------------------
extern "C" void kernel_launch(void* const* d_in, const int* in_sizes, int n_in,
                              void* d_out, int out_size, void* d_ws, size_t ws_size,
                              hipStream_t stream) {
    const float* src  = (const float*)d_in[0];
    const int*   eidx = (const int*)  d_in[1];
    const float* g1w  = (const float*)d_in[2];
    const float* g1b  = (const float*)d_in[3];
    const float* g2w  = (const float*)d_in[4];
    const float* g2b  = (const float*)d_in[5];
    const float* cv1w = (const float*)d_in[6];
    const float* cv1b = (const float*)d_in[7];
    const float* cv2w = (const float*)d_in[8];
    const float* cv2b = (const float*)d_in[9];
    const float* cv3w = (const float*)d_in[10];
    const float* cv3b = (const float*)d_in[11];
    const float* fc1w = (const float*)d_in[12];
    const float* fc1b = (const float*)d_in[13];
    const float* cl1w = (const float*)d_in[14];
    const float* cl1b = (const float*)d_in[15];
    const float* cl2w = (const float*)d_in[16];
    const float* cl2b = (const float*)d_in[17];

    unsigned short* ws16 = (unsigned short*)d_ws;
    float* wsF = (float*)d_ws;
    float* out = (float*)d_out;

    unsigned short* xt  = ws16 + R1_OFF;     // 96*8192*16, dead after agg_mm<16>
    unsigned short* xa  = ws16 + R0_OFF;     // 96*8192*16
    unsigned short* hw2 = ws16 + R1_OFF;     // overwrites dead xt
    unsigned short* h2  = ws16 + R0_OFF;     // overwrites dead xa
    unsigned short* c1  = ws16 + R1_OFF;
    unsigned short* c2  = ws16 + R0_OFF;
    unsigned short* c3  = ws16 + R1_OFF;
    float*          part = wsF;              // aliases dead c2 (R0)
    unsigned short* fr  = ws16 + FR_OFF;
    unsigned short* r2  = ws16 + R2_OFF;
    unsigned short* w1n = ws16 + W1N_OFF;
    unsigned short* w2n = ws16 + W2N_OFF;
    unsigned short* wc1 = ws16 + WC1_OFF;
    unsigned short* wc2 = ws16 + WC2_OFF;
    unsigned short* wc3 = ws16 + WC3_OFF;
    unsigned short* wf1 = ws16 + WF1_OFF;
    unsigned short* wl1 = ws16 + WL1_OFF;
    unsigned short* wl2 = ws16 + WL2_OFF;
    unsigned short* ah  = ws16 + AH_OFF;

    float* feat_out = out + 8192ull * 210ull;

    prep_edges<<<1, 256, 0, stream>>>(eidx, ah);
    prep_weights<<<2345, 256, 0, stream>>>(g1w, g2w, cv1w, cv2w, cv3w, fc1w, cl1w, cl2w,
                                           ws16 + WT_OFF);
    trans16<<<1024, 256, 0, stream>>>(src, xt);
    agg_mm<16, false><<<512, 256, 0, stream>>>(xt, ah, nullptr, xa);
    gcn12<<<dim3(64, 1, 96), 256, 0, stream>>>(xa, w1n, w2n, g1b, hw2);
    agg_mm<32, true><<<1024, 256, 0, stream>>>(hw2, ah, g2b, h2);
    gemm_slab<4, 7, 32, 64, 2, 3, 96, 32, 0>
        <<<dim3(64, 1, 48), 256, 0, stream>>>(h2, wc1, cv1b, c1, nullptr);
    gemm_slab<4, 5, 64, 128, 2, 2, 48, 64, 0>
        <<<dim3(64, 2, 24), 256, 0, stream>>>(c1, wc2, cv2b, c2, nullptr);
    gemm_slab<4, 3, 128, 256, 2, 1, 24, 64, 0>
        <<<dim3(64, 4, 12), 256, 0, stream>>>(c2, wc3, cv3b, c3, nullptr);
    fc1_splitk<<<dim3(64, 1, 6), 256, 0, stream>>>(c3, wf1, part);
    fc1_reduce<<<1024, 256, 0, stream>>>(part, fc1b, feat_out, fr);
    gemm_slab<2, 1, 128, 128, 1, 0, 1, 64, 0>
        <<<dim3(128, 2, 1), 256, 0, stream>>>(fr, wl1, cl1b, r2, nullptr);
    gemm_slab<2, 1, 128, 256, 1, 0, 1, 64, 4>
        <<<dim3(128, 4, 1), 256, 0, stream>>>(r2, wl2, cl2b, nullptr, out);
}

// Round 7
// 359.561 us; speedup vs baseline: 5.2526x; 1.0217x over previous
//
#include <hip/hip_runtime.h>

// ---------------------------------------------------------------------------
// TimeSeriesGCN — bf16 MFMA pipeline, batch-as-M GEMMs on position-major slabs.
// prep_edges:  edge_index -> dense bf16 Ahat[96][96]
// trans16:     src -> xt[96][8192][16] (bf16 transpose only)
// agg_mm<16>:  xt -> xa = Ahat @ xt            (dense-GEMM aggregation)
// gcn12:       xa(16ch) -> hw2[96][8192][32]
// agg_mm<32>:  hw2 -> h2 = relu(Ahat @ hw2 + b2)
// conv1 (256x64) / conv2 (128x128) / conv3 (128x128): slab GEMMs
// fc1_splitk:  c3 -> fp32 partials (6-way split-K, BN=128)
// fc1_reduce:  partials -> feat (fp32 d_out) + fr (bf16 relu)
// cls1: fr -> r2; cls2: r2 -> logits (fp32 d_out)
// ---------------------------------------------------------------------------

typedef __attribute__((ext_vector_type(8))) short short8v;
typedef __attribute__((ext_vector_type(4))) float floatx4;

#define N_NODE 96
#define E_TOT  864
#define BATCH  8192ull

// ws layout, ushort elements
#define R0_OFF   0ull
#define R1_OFF   25165824ull
#define FR_OFF   50331648ull
#define R2_OFF   51380224ull
#define WT_OFF   52428800ull
#define W1N_OFF  (WT_OFF + 0)
#define W2N_OFF  (WT_OFF + 2048)
#define WC1_OFF  (WT_OFF + 4096)
#define WC2_OFF  (WT_OFF + 18432)
#define WC3_OFF  (WT_OFF + 59392)
#define WF1_OFF  (WT_OFF + 157696)
#define WL1_OFF  (WT_OFF + 550912)
#define WL2_OFF  (WT_OFF + 567296)
#define AH_OFF   (WT_OFF + 600064)   // dense Ahat bf16 [96][96]

__device__ __forceinline__ unsigned short f2b(float f) {
    unsigned int u = __builtin_bit_cast(unsigned int, f);
    u += 0x7fffu + ((u >> 16) & 1u);
    return (unsigned short)(u >> 16);
}
__device__ __forceinline__ float b2f(unsigned short h) {
    unsigned int u = ((unsigned int)h) << 16;
    return __builtin_bit_cast(float, u);
}

// ---------------------------------------------------------------------------
__global__ void prep_edges(const int* __restrict__ eidx, unsigned short* __restrict__ adense) {
    __shared__ int rowv[E_TOT];
    __shared__ int colv[E_TOT];
    __shared__ int degi[N_NODE];
    __shared__ float dinv[N_NODE];
    __shared__ float ad[96 * 96];
    const int tid = threadIdx.x;
    for (int e = tid; e < E_TOT; e += 256) {
        int r, c;
        if (e < 768) { r = eidx[e]; c = eidx[768 + e]; }
        else         { r = e - 768; c = r; }
        rowv[e] = r; colv[e] = c;
    }
    for (int n = tid; n < N_NODE; n += 256) degi[n] = 0;
    for (int i = tid; i < 9216; i += 256) ad[i] = 0.f;
    __syncthreads();
    for (int e = tid; e < E_TOT; e += 256) atomicAdd(&degi[rowv[e]], 1);
    __syncthreads();
    for (int n = tid; n < N_NODE; n += 256)
        dinv[n] = rsqrtf(fmaxf((float)degi[n], 1e-12f));
    __syncthreads();
    for (int e = tid; e < E_TOT; e += 256)
        atomicAdd(&ad[rowv[e] * 96 + colv[e]], dinv[rowv[e]] * dinv[colv[e]]);
    __syncthreads();
    for (int i = tid; i < 9216; i += 256) adense[i] = f2b(ad[i]);
}

// ---------------------------------------------------------------------------
__global__ void prep_weights(const float* __restrict__ g1w, const float* __restrict__ g2w,
                             const float* __restrict__ w1, const float* __restrict__ w2,
                             const float* __restrict__ w3, const float* __restrict__ f1,
                             const float* __restrict__ l1, const float* __restrict__ l2,
                             unsigned short* __restrict__ wt) {
    long idx = (long)blockIdx.x * 256 + threadIdx.x;
    if (idx >= 600064) return;
    float v;
    if (idx < 2048) {
        int o = idx >> 5, c = idx & 31;
        v = (c < 16) ? g1w[c * 64 + o] : 0.f;
    } else if (idx < 4096) {
        long j = idx - 2048; int g = j >> 6, c = j & 63;
        v = g2w[c * 32 + g];
    } else if (idx < 18432) {
        long j = idx - 4096; int o = j / 224, m = j % 224, t = m >> 5, c = m & 31;
        v = w1[o * 224 + c * 7 + t];
    } else if (idx < 59392) {
        long j = idx - 18432; int o = j / 320, m = j % 320, t = m >> 6, c = m & 63;
        v = w2[o * 320 + c * 5 + t];
    } else if (idx < 157696) {
        long j = idx - 59392; int o = j / 384, m = j % 384, t = m >> 7, c = m & 127;
        v = w3[o * 384 + c * 3 + t];
    } else if (idx < 550912) {
        long j = idx - 157696; int f = j / 3072, m = j % 3072, t = m >> 8, o = m & 255;
        v = f1[(o * 12 + t) * 128 + f];
    } else if (idx < 567296) {
        long j = idx - 550912; int f2 = j >> 7, ff = j & 127;
        v = l1[ff * 128 + f2];
    } else {
        long j = idx - 567296; int n = j >> 7, f = j & 127;
        v = (n < 210) ? l2[f * 210 + n] : 0.f;
    }
    wt[idx] = f2b(v);
}

// ---------------------------------------------------------------------------
__launch_bounds__(256)
__global__ void trans16(const float* __restrict__ src, unsigned short* __restrict__ xt) {
    __shared__ __align__(16) float xs[8 * 1544];
    const int tid = threadIdx.x;
    const int b0 = blockIdx.x * 8;
    for (int u = tid; u < 3072; u += 256) {
        int bl = u / 384, j = u % 384;
        *(float4*)&xs[bl * 1544 + j * 4] =
            *(const float4*)&src[((size_t)(b0 + bl)) * 1536 + j * 4];
    }
    __syncthreads();
    for (int u = tid; u < 768; u += 256) {
        int n = u >> 3, bl = u & 7;
        const float* base = &xs[bl * 1544 + n];
        unsigned int d[8];
#pragma unroll
        for (int c2 = 0; c2 < 8; c2++)
            d[c2] = (unsigned int)f2b(base[(2 * c2) * 96]) |
                    ((unsigned int)f2b(base[(2 * c2 + 1) * 96]) << 16);
        unsigned int* o = (unsigned int*)(xt + ((size_t)n * BATCH + b0 + bl) * 16);
        *(uint4*)&o[0] = make_uint4(d[0], d[1], d[2], d[3]);
        *(uint4*)&o[4] = make_uint4(d[4], d[5], d[6], d[7]);
    }
}

// ---------------------------------------------------------------------------
template<int CH, bool RELU>
__launch_bounds__(256)
__global__ void agg_mm(const unsigned short* __restrict__ in,
                       const unsigned short* __restrict__ adense,
                       const float* __restrict__ bias,
                       unsigned short* __restrict__ outp) {
    const size_t NCOL = 8192ull * CH;
    __shared__ __align__(16) unsigned short Al[96 * 104];
    __shared__ __align__(16) unsigned short Bs[96 * 264];
    const int tid = threadIdx.x;
    const size_t c0 = (size_t)blockIdx.x * 256;
    const int w = tid >> 6, lane = tid & 63, quad = lane >> 4, m16 = lane & 15;

    for (int u = tid; u < 1152; u += 256) {
        int r = u / 12, q = u % 12;
        *(short8v*)&Al[r * 104 + q * 8] = *(const short8v*)&adense[r * 96 + q * 8];
    }
    for (int u = tid; u < 3072; u += 256) {
        int r = u >> 5, q = u & 31;
        *(uint4*)&Bs[r * 264 + q * 8] = *(const uint4*)&in[(size_t)r * NCOL + c0 + q * 8];
    }
    __syncthreads();

    floatx4 acc[6][4] = {};
    const int nb = w * 64;
#pragma unroll
    for (int kk = 0; kk < 96; kk += 32) {
        short8v bfr[4];
#pragma unroll
        for (int fn = 0; fn < 4; fn++) {
            const int col = nb + fn * 16 + m16;
#pragma unroll
            for (int j = 0; j < 8; j++)
                bfr[fn][j] = (short)Bs[(kk + quad * 8 + j) * 264 + col];
        }
#pragma unroll
        for (int fm = 0; fm < 6; fm++) {
            short8v afr = *(short8v*)&Al[(fm * 16 + m16) * 104 + kk + quad * 8];
#pragma unroll
            for (int fn = 0; fn < 4; fn++)
                acc[fm][fn] = __builtin_amdgcn_mfma_f32_16x16x32_bf16(afr, bfr[fn], acc[fm][fn], 0, 0, 0);
        }
    }

#pragma unroll
    for (int fm = 0; fm < 6; fm++) {
#pragma unroll
        for (int fn = 0; fn < 4; fn++) {
            const int col = nb + fn * 16 + m16;
            float bv = 0.f;
            if constexpr (RELU) bv = bias[col & (CH - 1)];
#pragma unroll
            for (int r = 0; r < 4; r++) {
                int node = fm * 16 + quad * 4 + r;
                float v = acc[fm][fn][r];
                if constexpr (RELU) v = fmaxf(v + bv, 0.f);
                outp[(size_t)node * NCOL + c0 + col] = f2b(v);
            }
        }
    }
}

// ---------------------------------------------------------------------------
__launch_bounds__(256)
__global__ void gcn12(const unsigned short* __restrict__ xa,
                      const unsigned short* __restrict__ w1n,
                      const unsigned short* __restrict__ w2n,
                      const float* __restrict__ b1, unsigned short* __restrict__ hw2) {
    __shared__ __align__(16) unsigned short As[128 * 40];
    __shared__ __align__(16) unsigned short B1s[64 * 40];
    __shared__ __align__(16) unsigned short H1s[128 * 72];
    __shared__ __align__(16) unsigned short B2s[32 * 72];
    const int tid = threadIdx.x;
    const size_t b0 = blockIdx.x * 128;
    const int l = blockIdx.z;
    const int w = tid >> 6, lane = tid & 63, quad = lane >> 4, m16 = lane & 15;

    short8v zz = {0, 0, 0, 0, 0, 0, 0, 0};
    for (int u = tid; u < 512; u += 256) {
        int r = u >> 2, cc = u & 3;
        *(short8v*)&As[r * 40 + cc * 8] = (cc < 2)
            ? *(const short8v*)&xa[((size_t)l * BATCH + b0 + r) * 16 + cc * 8]
            : zz;
    }
    for (int u = tid; u < 256; u += 256) {
        int r = u >> 2, cc = u & 3;
        *(short8v*)&B1s[r * 40 + cc * 8] = *(const short8v*)&w1n[r * 32 + cc * 8];
    }
    for (int u = tid; u < 256; u += 256) {
        int r = u >> 3, cc = u & 7;
        *(short8v*)&B2s[r * 72 + cc * 8] = *(const short8v*)&w2n[r * 64 + cc * 8];
    }
    __syncthreads();

    {
        const int wm = w >> 1, wq = w & 1;
        const int mbase = wm * 64, nbase = wq * 32;
        floatx4 acc[4][2] = {};
#pragma unroll
        for (int fn = 0; fn < 2; fn++) {
            short8v bfr = *(short8v*)&B1s[(nbase + fn * 16 + m16) * 40 + quad * 8];
#pragma unroll
            for (int fm = 0; fm < 4; fm++) {
                short8v afr = *(short8v*)&As[(mbase + fm * 16 + m16) * 40 + quad * 8];
                acc[fm][fn] = __builtin_amdgcn_mfma_f32_16x16x32_bf16(afr, bfr, acc[fm][fn], 0, 0, 0);
            }
        }
        float bv0 = b1[nbase + m16], bv1 = b1[nbase + 16 + m16];
#pragma unroll
        for (int fm = 0; fm < 4; fm++)
#pragma unroll
            for (int r = 0; r < 4; r++) {
                int row = mbase + fm * 16 + quad * 4 + r;
                H1s[row * 72 + nbase + m16]      = f2b(fmaxf(acc[fm][0][r] + bv0, 0.f));
                H1s[row * 72 + nbase + 16 + m16] = f2b(fmaxf(acc[fm][1][r] + bv1, 0.f));
            }
    }
    __syncthreads();

    {
        const int mb2 = w * 32;
        floatx4 acc[2][2] = {};
#pragma unroll
        for (int kk = 0; kk < 64; kk += 32)
#pragma unroll
            for (int fn = 0; fn < 2; fn++) {
                short8v bfr = *(short8v*)&B2s[(fn * 16 + m16) * 72 + kk + quad * 8];
#pragma unroll
                for (int fm = 0; fm < 2; fm++) {
                    short8v afr = *(short8v*)&H1s[(mb2 + fm * 16 + m16) * 72 + kk + quad * 8];
                    acc[fm][fn] = __builtin_amdgcn_mfma_f32_16x16x32_bf16(afr, bfr, acc[fm][fn], 0, 0, 0);
                }
            }
        unsigned short* Cs = As;
#pragma unroll
        for (int fm = 0; fm < 2; fm++)
#pragma unroll
            for (int r = 0; r < 4; r++) {
                int row = mb2 + fm * 16 + quad * 4 + r;
                Cs[row * 40 + m16]      = f2b(acc[fm][0][r]);
                Cs[row * 40 + 16 + m16] = f2b(acc[fm][1][r]);
            }
    }
    __syncthreads();
    for (int u = tid; u < 512; u += 256) {
        int r = u >> 2, cc = u & 3;
        *(short8v*)&hw2[((size_t)l * BATCH + b0 + r) * 32 + cc * 8] =
            *(short8v*)&As[r * 40 + cc * 8];
    }
}

// ---------------------------------------------------------------------------
// Unified slab GEMM. BM = WM*32 (2 m-waves), BN = FN*32 (2 n-waves).
// MODE 0: bf16 out + bias + relu. MODE 4: fp32 out [210-stride], masked.
// One LDS pool aliased: staging (As|Bs) during K-loop, C-tile in epilogue.
// ---------------------------------------------------------------------------
template<int WM, int FN, int NTAP, int CIN, int NOUT, int STRIDE, int PAD, int LIN, int BK, int MODE>
__launch_bounds__(256)
__global__ void gemm_slab(const unsigned short* __restrict__ in,
                          const unsigned short* __restrict__ wn,
                          const float* __restrict__ bias,
                          unsigned short* __restrict__ outb,
                          float* __restrict__ outf) {
    constexpr int BM  = WM * 32;
    constexpr int BN  = FN * 32;
    constexpr int BKP = BK + 8;
    constexpr int CPT = CIN / BK;
    constexpr int NC  = NTAP * CPT;
    constexpr int KTOT = NTAP * CIN;
    constexpr int SZ1 = BM * BKP + BN * BKP;
    constexpr int SZ2 = BM * (BN + 8);
    constexpr int POOL = SZ1 > SZ2 ? SZ1 : SZ2;
    __shared__ __align__(16) unsigned short pool[POOL];
    unsigned short* As = pool;
    unsigned short* Bs = pool + BM * BKP;
    const int tid = threadIdx.x;
    const size_t b0 = blockIdx.x * BM;
    const int n0 = blockIdx.y * BN;
    const int l  = blockIdx.z;
    const int w = tid >> 6, lane = tid & 63, quad = lane >> 4, m16 = lane & 15;
    const int wm = w >> 1, wq = w & 1;
    const int mbase = wm * (WM * 16), nbase = wq * (FN * 16);
    floatx4 acc[WM][FN] = {};

    for (int ch = 0; ch < NC; ++ch) {
        int t = ch / CPT, inner = ch % CPT;
        int pos = STRIDE * l + t - PAD;
        if (pos < 0 || pos >= LIN) continue;
        const unsigned short* ag = in + ((size_t)pos * BATCH + b0) * CIN + inner * BK;
        for (int u = tid; u < BM * (BK / 8); u += 256) {
            int r = u / (BK / 8), cc = u % (BK / 8);
            *(short8v*)&As[r * BKP + cc * 8] = *(const short8v*)&ag[(size_t)r * CIN + cc * 8];
        }
        const unsigned short* bg = wn + (size_t)n0 * KTOT + t * CIN + inner * BK;
        for (int u = tid; u < BN * (BK / 8); u += 256) {
            int r = u / (BK / 8), cc = u % (BK / 8);
            *(short8v*)&Bs[r * BKP + cc * 8] = *(const short8v*)&bg[(size_t)r * KTOT + cc * 8];
        }
        __syncthreads();
#pragma unroll
        for (int kk = 0; kk < BK; kk += 32) {
            short8v bfr[FN];
#pragma unroll
            for (int fn = 0; fn < FN; fn++)
                bfr[fn] = *(short8v*)&Bs[(nbase + fn * 16 + m16) * BKP + kk + quad * 8];
#pragma unroll
            for (int fm = 0; fm < WM; fm++) {
                short8v afr = *(short8v*)&As[(mbase + fm * 16 + m16) * BKP + kk + quad * 8];
#pragma unroll
                for (int fn = 0; fn < FN; fn++)
                    acc[fm][fn] = __builtin_amdgcn_mfma_f32_16x16x32_bf16(afr, bfr[fn], acc[fm][fn], 0, 0, 0);
            }
        }
        __syncthreads();
    }

    if constexpr (MODE == 4) {
#pragma unroll
        for (int fn = 0; fn < FN; fn++) {
            int cg = n0 + nbase + fn * 16 + m16;
            float bv = (cg < 210) ? bias[cg] : 0.f;
            if (cg < 210) {
#pragma unroll
                for (int fm = 0; fm < WM; fm++)
#pragma unroll
                    for (int r = 0; r < 4; r++) {
                        size_t row = b0 + mbase + fm * 16 + quad * 4 + r;
                        outf[row * 210 + cg] = acc[fm][fn][r] + bv;
                    }
            }
        }
    } else {
        float bv[FN];
#pragma unroll
        for (int fn = 0; fn < FN; fn++) bv[fn] = bias[n0 + nbase + fn * 16 + m16];
        unsigned short* Cs = pool;
#pragma unroll
        for (int fm = 0; fm < WM; fm++)
#pragma unroll
            for (int r = 0; r < 4; r++) {
                int row = mbase + fm * 16 + quad * 4 + r;
#pragma unroll
                for (int fn = 0; fn < FN; fn++)
                    Cs[row * (BN + 8) + nbase + fn * 16 + m16] =
                        f2b(fmaxf(acc[fm][fn][r] + bv[fn], 0.f));
            }
        __syncthreads();
        for (int u = tid; u < BM * (BN / 8); u += 256) {
            int r = u / (BN / 8), cc = u % (BN / 8);
            *(short8v*)&outb[((size_t)l * BATCH + b0 + r) * NOUT + n0 + cc * 8] =
                *(short8v*)&Cs[r * (BN + 8) + cc * 8];
        }
    }
}

// ---------------------------------------------------------------------------
// fc1 split-K: BN=128 (A read once). grid (64, 1, 6). Waves 2x2, each 64x64.
// ---------------------------------------------------------------------------
__launch_bounds__(256)
__global__ void fc1_splitk(const unsigned short* __restrict__ c3,
                           const unsigned short* __restrict__ wf1,
                           float* __restrict__ part) {
    __shared__ __align__(16) unsigned short As[128 * 72];
    __shared__ __align__(16) unsigned short Bs[128 * 72];
    const int tid = threadIdx.x;
    const size_t b0 = blockIdx.x * 128;
    const int kg = blockIdx.z;
    const int w = tid >> 6, lane = tid & 63, quad = lane >> 4, m16 = lane & 15;
    const int wm = w >> 1, wq = w & 1;
    const int mbase = wm * 64, nbase = wq * 64;
    floatx4 acc[4][4] = {};

#pragma unroll
    for (int tt = 0; tt < 2; tt++) {
        const int t = kg * 2 + tt;
#pragma unroll
        for (int inner = 0; inner < 4; inner++) {
            const unsigned short* ag = c3 + ((size_t)t * BATCH + b0) * 256 + inner * 64;
            for (int u = tid; u < 1024; u += 256) {
                int r = u >> 3, cc = u & 7;
                *(short8v*)&As[r * 72 + cc * 8] = *(const short8v*)&ag[(size_t)r * 256 + cc * 8];
            }
            const unsigned short* bg = wf1 + t * 256 + inner * 64;
            for (int u = tid; u < 1024; u += 256) {
                int r = u >> 3, cc = u & 7;
                *(short8v*)&Bs[r * 72 + cc * 8] = *(const short8v*)&bg[(size_t)r * 3072 + cc * 8];
            }
            __syncthreads();
#pragma unroll
            for (int kk = 0; kk < 64; kk += 32) {
                short8v bfr[4];
#pragma unroll
                for (int fn = 0; fn < 4; fn++)
                    bfr[fn] = *(short8v*)&Bs[(nbase + fn * 16 + m16) * 72 + kk + quad * 8];
#pragma unroll
                for (int fm = 0; fm < 4; fm++) {
                    short8v afr = *(short8v*)&As[(mbase + fm * 16 + m16) * 72 + kk + quad * 8];
#pragma unroll
                    for (int fn = 0; fn < 4; fn++)
                        acc[fm][fn] = __builtin_amdgcn_mfma_f32_16x16x32_bf16(afr, bfr[fn], acc[fm][fn], 0, 0, 0);
                }
            }
            __syncthreads();
        }
    }
    float* pg = part + (size_t)kg * BATCH * 128;
#pragma unroll
    for (int fm = 0; fm < 4; fm++)
#pragma unroll
        for (int r = 0; r < 4; r++) {
            size_t row = b0 + mbase + fm * 16 + quad * 4 + r;
#pragma unroll
            for (int fn = 0; fn < 4; fn++)
                pg[row * 128 + nbase + fn * 16 + m16] = acc[fm][fn][r];
        }
}

// ---------------------------------------------------------------------------
__launch_bounds__(256)
__global__ void fc1_reduce(const float* __restrict__ part, const float* __restrict__ bias,
                           float* __restrict__ feat, unsigned short* __restrict__ fr) {
    const size_t idx = (size_t)blockIdx.x * 256 + threadIdx.x;
    const size_t row = idx >> 5;
    const int    c4  = (int)(idx & 31);
    float4 s = *(const float4*)&bias[c4 * 4];
#pragma unroll
    for (int z = 0; z < 6; z++) {
        float4 p = *(const float4*)&part[(z * BATCH + row) * 128 + c4 * 4];
        s.x += p.x; s.y += p.y; s.z += p.z; s.w += p.w;
    }
    *(float4*)&feat[row * 128 + c4 * 4] = s;
    unsigned int d0 = (unsigned int)f2b(fmaxf(s.x, 0.f)) |
                      ((unsigned int)f2b(fmaxf(s.y, 0.f)) << 16);
    unsigned int d1 = (unsigned int)f2b(fmaxf(s.z, 0.f)) |
                      ((unsigned int)f2b(fmaxf(s.w, 0.f)) << 16);
    *(uint2*)&fr[row * 128 + c4 * 4] = make_uint2(d0, d1);
}

// ---------------------------------------------------------------------------
extern "C" void kernel_launch(void* const* d_in, const int* in_sizes, int n_in,
                              void* d_out, int out_size, void* d_ws, size_t ws_size,
                              hipStream_t stream) {
    const float* src  = (const float*)d_in[0];
    const int*   eidx = (const int*)  d_in[1];
    const float* g1w  = (const float*)d_in[2];
    const float* g1b  = (const float*)d_in[3];
    const float* g2w  = (const float*)d_in[4];
    const float* g2b  = (const float*)d_in[5];
    const float* cv1w = (const float*)d_in[6];
    const float* cv1b = (const float*)d_in[7];
    const float* cv2w = (const float*)d_in[8];
    const float* cv2b = (const float*)d_in[9];
    const float* cv3w = (const float*)d_in[10];
    const float* cv3b = (const float*)d_in[11];
    const float* fc1w = (const float*)d_in[12];
    const float* fc1b = (const float*)d_in[13];
    const float* cl1w = (const float*)d_in[14];
    const float* cl1b = (const float*)d_in[15];
    const float* cl2w = (const float*)d_in[16];
    const float* cl2b = (const float*)d_in[17];

    unsigned short* ws16 = (unsigned short*)d_ws;
    float* wsF = (float*)d_ws;
    float* out = (float*)d_out;

    unsigned short* xt  = ws16 + R1_OFF;
    unsigned short* xa  = ws16 + R0_OFF;
    unsigned short* hw2 = ws16 + R1_OFF;
    unsigned short* h2  = ws16 + R0_OFF;
    unsigned short* c1  = ws16 + R1_OFF;
    unsigned short* c2  = ws16 + R0_OFF;
    unsigned short* c3  = ws16 + R1_OFF;
    float*          part = wsF;              // aliases dead c2 (R0)
    unsigned short* fr  = ws16 + FR_OFF;
    unsigned short* r2  = ws16 + R2_OFF;
    unsigned short* w1n = ws16 + W1N_OFF;
    unsigned short* w2n = ws16 + W2N_OFF;
    unsigned short* wc1 = ws16 + WC1_OFF;
    unsigned short* wc2 = ws16 + WC2_OFF;
    unsigned short* wc3 = ws16 + WC3_OFF;
    unsigned short* wf1 = ws16 + WF1_OFF;
    unsigned short* wl1 = ws16 + WL1_OFF;
    unsigned short* wl2 = ws16 + WL2_OFF;
    unsigned short* ah  = ws16 + AH_OFF;

    float* feat_out = out + 8192ull * 210ull;

    prep_edges<<<1, 256, 0, stream>>>(eidx, ah);
    prep_weights<<<2345, 256, 0, stream>>>(g1w, g2w, cv1w, cv2w, cv3w, fc1w, cl1w, cl2w,
                                           ws16 + WT_OFF);
    trans16<<<1024, 256, 0, stream>>>(src, xt);
    agg_mm<16, false><<<512, 256, 0, stream>>>(xt, ah, nullptr, xa);
    gcn12<<<dim3(64, 1, 96), 256, 0, stream>>>(xa, w1n, w2n, g1b, hw2);
    agg_mm<32, true><<<1024, 256, 0, stream>>>(hw2, ah, g2b, h2);
    // conv1: BM=256, BN=64
    gemm_slab<8, 2, 7, 32, 64, 2, 3, 96, 32, 0>
        <<<dim3(32, 1, 48), 256, 0, stream>>>(h2, wc1, cv1b, c1, nullptr);
    // conv2: BM=128, BN=128
    gemm_slab<4, 4, 5, 64, 128, 2, 2, 48, 64, 0>
        <<<dim3(64, 1, 24), 256, 0, stream>>>(c1, wc2, cv2b, c2, nullptr);
    // conv3: BM=128, BN=128 (y=2)
    gemm_slab<4, 4, 3, 128, 256, 2, 1, 24, 64, 0>
        <<<dim3(64, 2, 12), 256, 0, stream>>>(c2, wc3, cv3b, c3, nullptr);
    fc1_splitk<<<dim3(64, 1, 6), 256, 0, stream>>>(c3, wf1, part);
    fc1_reduce<<<1024, 256, 0, stream>>>(part, fc1b, feat_out, fr);
    gemm_slab<2, 2, 1, 128, 128, 1, 0, 1, 64, 0>
        <<<dim3(128, 2, 1), 256, 0, stream>>>(fr, wl1, cl1b, r2, nullptr);
    gemm_slab<2, 2, 1, 128, 256, 1, 0, 1, 64, 4>
        <<<dim3(128, 4, 1), 256, 0, stream>>>(r2, wl2, cl2b, nullptr, out);
}